// Round 8
// baseline (640.444 us; speedup 1.0000x reference)
//
#include <hip/hip_runtime.h>
#include <hip/hip_bf16.h>

#define N_NODES 50000
#define N_EDGES 800000
#define N_GRAPHS 128
#define HID 128
#define NK 3
#define NL 4
#define NC 10
#define BN_EPS 1e-5f
#define SCAN_G ((N_NODES + 255) / 256)

// degree histogram bucketing
#define BKT_SZ 8192
#define NBKT 7                    // ceil(50000/8192)
#define NCHK 64
#define CHK_E (N_EDGES / NCHK)    // 12500

typedef __attribute__((ext_vector_type(8))) _Float16 half8;
typedef __attribute__((ext_vector_type(4))) float floatx4;
typedef __attribute__((ext_vector_type(2))) float float2v;
typedef __attribute__((ext_vector_type(2))) _Float16 half2v;
typedef __attribute__((ext_vector_type(4))) _Float16 half4v;

__device__ __forceinline__ float tanh_fast(float x) {
    float ax = fabsf(x);
    float t = __expf(-2.0f * ax);
    float r = (1.0f - t) / (1.0f + t);
    return copysignf(r, x);
}

// ------- degree histogram: per-(bucket,chunk) partials, LDS atomics only
// blockIdx.y: 0 = row array, 1 = col array
__global__ __launch_bounds__(256) void hist_part_kernel(const int* __restrict__ row,
                                                        const int* __restrict__ col,
                                                        int* __restrict__ pr,
                                                        int* __restrict__ pc) {
    __shared__ int hh[BKT_SZ];
    int b = blockIdx.x / NCHK, c = blockIdx.x % NCHK;
    const int* arr = blockIdx.y ? col : row;
    int* out = blockIdx.y ? pc : pr;
    int tid = threadIdx.x;
    for (int i = tid; i < BKT_SZ; i += 256) hh[i] = 0;
    __syncthreads();
    int base = b * BKT_SZ;
    int e0 = c * CHK_E, e1 = e0 + CHK_E;
    for (int e = e0 + tid; e < e1; e += 256) {
        int uv = arr[e] - base;
        if ((unsigned)uv < BKT_SZ) atomicAdd(&hh[uv], 1);
    }
    __syncthreads();
    size_t ob = ((size_t)b * NCHK + c) * BKT_SZ;
    for (int i = tid; i < BKT_SZ; i += 256) out[ob + i] = hh[i];
}

// reduce partials -> degr/degc
__global__ __launch_bounds__(256) void hist_reduce_kernel(const int* __restrict__ pr,
                                                          const int* __restrict__ pc,
                                                          int* __restrict__ degr,
                                                          int* __restrict__ degc) {
    int n = blockIdx.x * 256 + threadIdx.x;
    if (n >= N_NODES) return;
    int b = n / BKT_SZ, off = n - b * BKT_SZ;
    size_t base = (size_t)b * NCHK * BKT_SZ + off;
    int sr = 0, sc = 0;
    for (int c = 0; c < NCHK; ++c) {
        size_t idx = base + (size_t)c * BKT_SZ;
        sr += pr[idx];
        sc += pc[idx];
    }
    degr[n] = sr;
    degc[n] = sc;
}

// ------------------------------------------------ hierarchical scan (3 kernels)
__global__ __launch_bounds__(256) void scan1_kernel(const int* __restrict__ degc,
                                                    int* __restrict__ csr_off,
                                                    int* __restrict__ blocksum) {
    __shared__ int buf[256];
    int tid = threadIdx.x;
    int i = blockIdx.x * 256 + tid;
    int v = (i < N_NODES) ? degc[i] : 0;
    buf[tid] = v;
    __syncthreads();
    for (int d = 1; d < 256; d <<= 1) {
        int t = (tid >= d) ? buf[tid - d] : 0;
        __syncthreads();
        buf[tid] += t;
        __syncthreads();
    }
    if (i < N_NODES) csr_off[i] = buf[tid] - v;
    if (tid == 255) blocksum[blockIdx.x] = buf[255];
}

__global__ __launch_bounds__(256) void scan2_kernel(int* __restrict__ blocksum) {
    __shared__ int buf[256];
    int tid = threadIdx.x;
    int v = (tid < SCAN_G) ? blocksum[tid] : 0;
    buf[tid] = v;
    __syncthreads();
    for (int d = 1; d < 256; d <<= 1) {
        int t = (tid >= d) ? buf[tid - d] : 0;
        __syncthreads();
        buf[tid] += t;
        __syncthreads();
    }
    if (tid < SCAN_G) blocksum[tid] = buf[tid] - v;   // exclusive, in place
}

__global__ __launch_bounds__(256) void scan3_kernel(const int* __restrict__ blocksum,
                                                    int* __restrict__ csr_off,
                                                    int* __restrict__ cursor) {
    int i = blockIdx.x * 256 + threadIdx.x;
    if (i < N_NODES) {
        int v = csr_off[i] + blocksum[blockIdx.x];
        csr_off[i] = v;
        cursor[i] = v;
    }
    if (i == 0) csr_off[N_NODES] = N_EDGES;
}

// --------------- counting-sort scatter via global atomic cursors
__global__ void fill_csr_kernel(const int* __restrict__ row, const int* __restrict__ col,
                                const int* __restrict__ degr, const int* __restrict__ degc,
                                int* __restrict__ cursor, int* __restrict__ row_off,
                                float2* __restrict__ pseudo_s) {
    int e = blockIdx.x * blockDim.x + threadIdx.x;
    if (e >= N_EDGES) return;
    int r = row[e], c = col[e];
    int pos = atomicAdd(&cursor[c], 1);
    row_off[pos] = r << 9;   // byte offset into fp32 h row (512 B)
    pseudo_s[pos] = make_float2(rsqrtf((float)degr[r] + 1.0f),
                                rsqrtf((float)degc[c] + 1.0f));
}

// -------------------- per-edge weights for ALL layers in one pass
__global__ void edge_w_all_kernel(const float2* __restrict__ ps_in,
                                  const float* __restrict__ pp_w, const float* __restrict__ pp_b,
                                  const float* __restrict__ mu, const float* __restrict__ isig,
                                  float4* __restrict__ wE) {
    int e = blockIdx.x * blockDim.x + threadIdx.x;
    if (e >= N_EDGES) return;
    float2 p = ps_in[e];
#pragma unroll
    for (int l = 0; l < NL; ++l) {
        float ps0 = tanh_fast(p.x * pp_w[l * 4 + 0] + p.y * pp_w[l * 4 + 1] + pp_b[l * 2 + 0]);
        float ps1 = tanh_fast(p.x * pp_w[l * 4 + 2] + p.y * pp_w[l * 4 + 3] + pp_b[l * 2 + 1]);
        float w[NK];
#pragma unroll
        for (int k = 0; k < NK; ++k) {
            float d0 = ps0 - mu[l * 6 + k * 2 + 0], d1 = ps1 - mu[l * 6 + k * 2 + 1];
            float s0 = isig[l * 6 + k * 2 + 0],     s1 = isig[l * 6 + k * 2 + 1];
            w[k] = __expf(-0.5f * (d0 * d0 * s0 * s0 + d1 * d1 * s1 * s1));
        }
        wE[(size_t)l * N_EDGES + e] = make_float4(w[0], w[1], w[2], 0.0f);
    }
}

// ------------------------------- fp32 -> fp16 convert (vectorized)
__global__ void cvt16_kernel(const float4* __restrict__ src, half4v* __restrict__ dst, int n4) {
    int i = blockIdx.x * blockDim.x + threadIdx.x;
    if (i >= n4) return;
    float4 f = src[i];
    half4v o;
    o.x = (_Float16)f.x; o.y = (_Float16)f.y; o.z = (_Float16)f.z; o.w = (_Float16)f.w;
    dst[i] = o;
}

// ---------- fc_w transpose -> fp16: w2t[l][j][k*H+i] = fc_w[l][k*H+j][i]
__global__ void transpose_fc16_kernel(const float* __restrict__ fc_w,
                                      _Float16* __restrict__ w2t) {
    int idx = blockIdx.x * blockDim.x + threadIdx.x;
    if (idx >= NL * NK * HID * HID) return;
    int i = idx & (HID - 1);
    int j = (idx >> 7) & (HID - 1);
    int kl = idx >> 14;          // l*3 + k
    int k = kl % 3;
    int l = kl / 3;
    w2t[((size_t)(l * HID + j)) * (NK * HID) + k * HID + i] = (_Float16)fc_w[idx];
}

// -------------------------------------------------- fp16 MFMA GEMM
// C[M x 128] = A[M x Kd] @ W[128 x Kd]^T (+bias). 128x128 block tile.
// Optional fused BN stats.
__global__ __launch_bounds__(256) void gemm_f16_kernel(
        const _Float16* __restrict__ A, const _Float16* __restrict__ W,
        const float* __restrict__ bias, float* __restrict__ C,
        float* __restrict__ bnsum, int M, int Kd) {
    __shared__ _Float16 sA[128 * 40], sB[128 * 40];   // stride 40 halfs
    __shared__ float bsum[HID], bsq[HID];
    int tid = threadIdx.x;
    if (bnsum && tid < HID) { bsum[tid] = 0.f; bsq[tid] = 0.f; }
    int bm = blockIdx.x * 128;
    int wave = tid >> 6, lane = tid & 63;
    int ln = lane & 15, quad = lane >> 4;
    int wy = wave >> 1, wx = wave & 1;
    int srow = tid >> 2, scol = (tid & 3) << 3;
    floatx4 acc[4][4] = {};
    const half8 zv = {0, 0, 0, 0, 0, 0, 0, 0};

    half8 pA[2], pB[2];
    bool av0 = (bm + srow) < M, av1 = (bm + srow + 64) < M;
    const size_t aoff0 = (size_t)(bm + srow) * Kd + scol;
    const size_t aoff1 = (size_t)(bm + srow + 64) * Kd + scol;
    const size_t woff0 = (size_t)srow * Kd + scol;
    const size_t woff1 = (size_t)(srow + 64) * Kd + scol;

#define LOAD_TILE(K0)                                                          \
    do {                                                                       \
        pB[0] = *(const half8*)(W + woff0 + (K0));                             \
        pB[1] = *(const half8*)(W + woff1 + (K0));                             \
        pA[0] = av0 ? *(const half8*)(A + aoff0 + (K0)) : zv;                  \
        pA[1] = av1 ? *(const half8*)(A + aoff1 + (K0)) : zv;                  \
    } while (0)

    LOAD_TILE(0);
    for (int k0 = 0; k0 < Kd; k0 += 32) {
        __syncthreads();
#pragma unroll
        for (int rep = 0; rep < 2; ++rep) {
            int r = srow + rep * 64;
            *(half8*)&sA[r * 40 + scol] = pA[rep];
            *(half8*)&sB[r * 40 + scol] = pB[rep];
        }
        __syncthreads();
        if (k0 + 32 < Kd) LOAD_TILE(k0 + 32);   // overlaps with MFMA below
        half8 a[4], b[4];
        int kq = quad * 8;
#pragma unroll
        for (int i = 0; i < 4; ++i) {
            a[i] = *(const half8*)&sA[(wy * 64 + i * 16 + ln) * 40 + kq];
            b[i] = *(const half8*)&sB[(wx * 64 + i * 16 + ln) * 40 + kq];
        }
#pragma unroll
        for (int i = 0; i < 4; ++i)
#pragma unroll
            for (int j = 0; j < 4; ++j)
                acc[i][j] = __builtin_amdgcn_mfma_f32_16x16x32_f16(a[i], b[j], acc[i][j], 0, 0, 0);
    }
#undef LOAD_TILE

    // epilogue: C/D layout col = lane&15, row = quad*4 + reg
#pragma unroll
    for (int j = 0; j < 4; ++j) {
        int gc = wx * 64 + j * 16 + ln;
        float bv = bias ? bias[gc] : 0.f;
#pragma unroll
        for (int i = 0; i < 4; ++i) {
#pragma unroll
            for (int r = 0; r < 4; ++r) {
                int gr = bm + wy * 64 + i * 16 + quad * 4 + r;
                if (gr < M) C[(size_t)gr * HID + gc] = acc[i][j][r] + bv;
            }
        }
    }
    if (bnsum) {
        // rows beyond M accumulated zeros (A loaded as 0, no bias) -> safe
#pragma unroll
        for (int j = 0; j < 4; ++j) {
            float s = 0.f, q = 0.f;
#pragma unroll
            for (int i = 0; i < 4; ++i)
#pragma unroll
                for (int r = 0; r < 4; ++r) { float v = acc[i][j][r]; s += v; q += v * v; }
            s += __shfl_xor(s, 16); s += __shfl_xor(s, 32);
            q += __shfl_xor(q, 16); q += __shfl_xor(q, 32);
            if (quad == 0) {
                atomicAdd(&bsum[wx * 64 + j * 16 + ln], s);
                atomicAdd(&bsq[wx * 64 + j * 16 + ln], q);
            }
        }
        __syncthreads();
        if (tid < HID) {
            atomicAdd(&bnsum[tid],       bsum[tid]);
            atomicAdd(&bnsum[HID + tid], bsq[tid]);
        }
    }
}

// ----------- CSR aggregation gathering fp32 h; emits u fp16 [N][384]
// metadata for 64 edges loaded once per wave, broadcast via shfl; pk_fma accum
__global__ __launch_bounds__(256) void aggregate_kernel(const int* __restrict__ csr_off,
                                                        const int* __restrict__ row_off,
                                                        const float4* __restrict__ wE,
                                                        const char* __restrict__ h,
                                                        _Float16* __restrict__ u) {
    int wave = threadIdx.x >> 6;
    int lane = threadIdx.x & 63;
    int n = blockIdx.x * 4 + wave;
    if (n >= N_NODES) return;
    int beg = csr_off[n], end = csr_off[n + 1];
    const char* hb = h + lane * 8;
    float2v a0 = {0.f, 0.f}, a1 = {0.f, 0.f}, a2 = {0.f, 0.f};
    for (int chunk = beg; chunk < end; chunk += 64) {
        int ce = chunk + lane;
        int roff = 0;
        float4 wv = make_float4(0.f, 0.f, 0.f, 0.f);
        if (ce < end) { roff = row_off[ce]; wv = wE[ce]; }
        int m = end - chunk; if (m > 64) m = 64;
        int t = 0;
        for (; t + 8 <= m; t += 8) {
            int ro[8];
#pragma unroll
            for (int s = 0; s < 8; ++s) ro[s] = __shfl(roff, t + s);
            float2v hv[8];
#pragma unroll
            for (int s = 0; s < 8; ++s) hv[s] = *(const float2v*)(hb + (unsigned)ro[s]);
            float wx[8], wy[8], wz[8];
#pragma unroll
            for (int s = 0; s < 8; ++s) {
                wx[s] = __shfl(wv.x, t + s);
                wy[s] = __shfl(wv.y, t + s);
                wz[s] = __shfl(wv.z, t + s);
            }
#pragma unroll
            for (int s = 0; s < 8; ++s) {
                a0 += wx[s] * hv[s];
                a1 += wy[s] * hv[s];
                a2 += wz[s] * hv[s];
            }
        }
        for (; t < m; ++t) {
            int ro = __shfl(roff, t);
            float wx = __shfl(wv.x, t), wy = __shfl(wv.y, t), wz = __shfl(wv.z, t);
            float2v hv = *(const float2v*)(hb + (unsigned)ro);
            a0 += wx * hv;
            a1 += wy * hv;
            a2 += wz * hv;
        }
    }
    size_t base = (size_t)n * 384 + lane * 2;
    half2v o0, o1, o2;
    o0.x = (_Float16)a0.x; o0.y = (_Float16)a0.y;
    o1.x = (_Float16)a1.x; o1.y = (_Float16)a1.y;
    o2.x = (_Float16)a2.x; o2.y = (_Float16)a2.y;
    *(half2v*)(u + base)       = o0;
    *(half2v*)(u + base + 128) = o1;
    *(half2v*)(u + base + 256) = o2;
}

// --------------------- BN apply + ReLU + residual
__global__ void bn_apply_kernel(float4* __restrict__ h4, const float4* __restrict__ agg4,
                                const float* __restrict__ bnsum,
                                const float* __restrict__ gamma, const float* __restrict__ beta) {
    int idx = blockIdx.x * blockDim.x + threadIdx.x;
    if (idx >= N_NODES * HID / 4) return;
    int c = (idx & 31) * 4;
    const float invN = 1.0f / (float)N_NODES;
    float4 a = agg4[idx];
    float4 hv = h4[idx];
    float av[4] = {a.x, a.y, a.z, a.w};
    float hh[4] = {hv.x, hv.y, hv.z, hv.w};
    float o[4];
#pragma unroll
    for (int j = 0; j < 4; ++j) {
        float mean = bnsum[c + j] * invN;
        float var = bnsum[HID + c + j] * invN - mean * mean;
        float hn = (av[j] - mean) * rsqrtf(var + BN_EPS) * gamma[c + j] + beta[c + j];
        o[j] = hh[j] + fmaxf(hn, 0.f);
    }
    h4[idx] = make_float4(o[0], o[1], o[2], o[3]);
}

// -------------------------------------------- fused readout + 3-layer MLP
__global__ __launch_bounds__(128) void readout_mlp_kernel(const float* __restrict__ h,
                                                          const int* __restrict__ batch,
                                                          const float* __restrict__ w0, const float* __restrict__ b0,
                                                          const float* __restrict__ w1, const float* __restrict__ b1,
                                                          const float* __restrict__ w2, const float* __restrict__ b2,
                                                          float* __restrict__ out) {
    __shared__ float hg[128];
    __shared__ float z0[64];
    __shared__ float z1[32];
    __shared__ int range[2];
    int g = blockIdx.x;
    int tid = threadIdx.x;
    if (tid == 0) {
        int lo = 0, hi = N_NODES;
        while (lo < hi) { int mid = (lo + hi) >> 1; if (batch[mid] < g) lo = mid + 1; else hi = mid; }
        range[0] = lo;
        hi = N_NODES;
        while (lo < hi) { int mid = (lo + hi) >> 1; if (batch[mid] < g + 1) lo = mid + 1; else hi = mid; }
        range[1] = lo;
    }
    __syncthreads();
    int lo = range[0], hi = range[1];
    float s0 = 0.f, s1 = 0.f, s2 = 0.f, s3 = 0.f;
    int n = lo;
    for (; n + 4 <= hi; n += 4) {
        s0 += h[(size_t)n * HID + tid];
        s1 += h[(size_t)(n + 1) * HID + tid];
        s2 += h[(size_t)(n + 2) * HID + tid];
        s3 += h[(size_t)(n + 3) * HID + tid];
    }
    for (; n < hi; ++n) s0 += h[(size_t)n * HID + tid];
    float s = (s0 + s1) + (s2 + s3);
    int cnt = hi - lo; if (cnt < 1) cnt = 1;
    hg[tid] = s / (float)cnt;
    __syncthreads();
    if (tid < 64) {
        float a = b0[tid];
        for (int i = 0; i < 128; ++i) a += hg[i] * w0[tid * 128 + i];
        z0[tid] = fmaxf(a, 0.f);
    }
    __syncthreads();
    if (tid < 32) {
        float a = b1[tid];
        for (int i = 0; i < 64; ++i) a += z0[i] * w1[tid * 64 + i];
        z1[tid] = fmaxf(a, 0.f);
    }
    __syncthreads();
    if (tid < 10) {
        float a = b2[tid];
        for (int i = 0; i < 32; ++i) a += z1[i] * w2[tid * 32 + i];
        out[g * NC + tid] = a;
    }
}

// ----------------------------------------------------------------- launch
extern "C" void kernel_launch(void* const* d_in, const int* in_sizes, int n_in,
                              void* d_out, int out_size, void* d_ws, size_t ws_size,
                              hipStream_t stream) {
    const float* feature = (const float*)d_in[0];
    const int*   edge    = (const int*)d_in[1];
    const int*   row     = edge;
    const int*   col     = edge + N_EDGES;
    const int*   batch   = (const int*)d_in[2];
    const float* emb_w   = (const float*)d_in[3];
    const float* emb_b   = (const float*)d_in[4];
    const float* fc_w    = (const float*)d_in[5];
    const float* mu      = (const float*)d_in[6];
    const float* isig    = (const float*)d_in[7];
    const float* gamma   = (const float*)d_in[8];
    const float* beta    = (const float*)d_in[9];
    const float* pp_w    = (const float*)d_in[10];
    const float* pp_b    = (const float*)d_in[11];
    const float* mw0     = (const float*)d_in[12];
    const float* mb0     = (const float*)d_in[13];
    const float* mw1     = (const float*)d_in[14];
    const float* mb1     = (const float*)d_in[15];
    const float* mw2     = (const float*)d_in[16];
    const float* mb2     = (const float*)d_in[17];
    float* out = (float*)d_out;

    // workspace carve-up (256B aligned)
    char* ws = (char*)d_ws;
    size_t off = 0;
    auto carve = [&](size_t bytes) { size_t o = off; off = (off + bytes + 255) & ~(size_t)255; return o; };
    float* h        = (float*)(ws + carve((size_t)N_NODES * HID * 4));
    _Float16* u     = (_Float16*)(ws + carve((size_t)N_NODES * NK * HID * 2));
    float* agg      = (float*)(ws + carve((size_t)N_NODES * HID * 4));
    float2* pseudo_s= (float2*)(ws + carve((size_t)N_EDGES * 2 * 4));
    float4* wE      = (float4*)(ws + carve((size_t)NL * N_EDGES * 4 * 4));
    _Float16* w2t   = (_Float16*)(ws + carve((size_t)NL * HID * NK * HID * 2));
    _Float16* f16   = (_Float16*)(ws + carve((size_t)N_NODES * HID * 2));
    _Float16* e16   = (_Float16*)(ws + carve((size_t)HID * HID * 2));
    int* degr       = (int*)(ws + carve((size_t)N_NODES * 4));
    int* degc       = (int*)(ws + carve((size_t)N_NODES * 4));
    int* csr_off    = (int*)(ws + carve((size_t)(N_NODES + 1) * 4));
    int* cursor     = (int*)(ws + carve((size_t)N_NODES * 4));
    int* row_off    = (int*)(ws + carve((size_t)N_EDGES * 4));
    int* blocksum   = (int*)(ws + carve((size_t)SCAN_G * 4));
    int* pr         = (int*)(ws + carve((size_t)NBKT * NCHK * BKT_SZ * 4));
    int* pc         = (int*)(ws + carve((size_t)NBKT * NCHK * BKT_SZ * 4));
    float* bnsum    = (float*)(ws + carve((size_t)NL * 2 * HID * 4));
    (void)ws_size; (void)in_sizes; (void)n_in; (void)out_size;

    hipMemsetAsync(bnsum, 0, (size_t)NL * 2 * HID * 4, stream);

    hist_part_kernel<<<dim3(NBKT * NCHK, 2), 256, 0, stream>>>(row, col, pr, pc);
    hist_reduce_kernel<<<(N_NODES + 255) / 256, 256, 0, stream>>>(pr, pc, degr, degc);
    scan1_kernel<<<SCAN_G, 256, 0, stream>>>(degc, csr_off, blocksum);
    scan2_kernel<<<1, 256, 0, stream>>>(blocksum);
    scan3_kernel<<<SCAN_G, 256, 0, stream>>>(blocksum, csr_off, cursor);
    fill_csr_kernel<<<(N_EDGES + 255) / 256, 256, 0, stream>>>(row, col, degr, degc, cursor,
                                                               row_off, pseudo_s);
    edge_w_all_kernel<<<(N_EDGES + 255) / 256, 256, 0, stream>>>(pseudo_s, pp_w, pp_b, mu, isig, wE);

    cvt16_kernel<<<(N_NODES * HID / 4 + 255) / 256, 256, 0, stream>>>(
        (const float4*)feature, (half4v*)f16, N_NODES * HID / 4);
    cvt16_kernel<<<(HID * HID / 4 + 255) / 256, 256, 0, stream>>>(
        (const float4*)emb_w, (half4v*)e16, HID * HID / 4);
    transpose_fc16_kernel<<<(NL * NK * HID * HID + 255) / 256, 256, 0, stream>>>(fc_w, w2t);

    // h = feature @ emb_w^T + emb_b
    gemm_f16_kernel<<<(N_NODES + 127) / 128, 256, 0, stream>>>(
        f16, e16, emb_b, h, nullptr, N_NODES, HID);

    for (int l = 0; l < NL; ++l) {
        aggregate_kernel<<<(N_NODES + 3) / 4, 256, 0, stream>>>(
            csr_off, row_off, wE + (size_t)l * N_EDGES, (const char*)h, u);
        gemm_f16_kernel<<<(N_NODES + 127) / 128, 256, 0, stream>>>(
            u, w2t + (size_t)l * HID * NK * HID, nullptr, agg,
            bnsum + l * 2 * HID, N_NODES, NK * HID);
        bn_apply_kernel<<<(N_NODES * HID / 4 + 255) / 256, 256, 0, stream>>>(
            (float4*)h, (const float4*)agg, bnsum + l * 2 * HID,
            gamma + l * HID, beta + l * HID);
    }

    readout_mlp_kernel<<<N_GRAPHS, 128, 0, stream>>>(h, batch, mw0, mb0, mw1, mb1, mw2, mb2, out);
}

// Round 9
// 569.154 us; speedup vs baseline: 1.1253x; 1.1253x over previous
//
#include <hip/hip_runtime.h>
#include <hip/hip_bf16.h>

#define N_NODES 50000
#define N_EDGES 800000
#define N_GRAPHS 128
#define HID 128
#define NK 3
#define NL 4
#define NC 10
#define BN_EPS 1e-5f
#define SCAN_G ((N_NODES + 255) / 256)

// degree histogram bucketing
#define BKT_SZ 8192
#define NBKT 7                    // ceil(50000/8192)
#define NCHK 64
#define CHK_E (N_EDGES / NCHK)    // 12500

typedef __attribute__((ext_vector_type(8))) _Float16 half8;
typedef __attribute__((ext_vector_type(4))) float floatx4;
typedef __attribute__((ext_vector_type(2))) float float2v;
typedef __attribute__((ext_vector_type(2))) _Float16 half2v;
typedef __attribute__((ext_vector_type(4))) _Float16 half4v;

__device__ __forceinline__ float tanh_fast(float x) {
    float ax = fabsf(x);
    float t = __expf(-2.0f * ax);
    float r = (1.0f - t) / (1.0f + t);
    return copysignf(r, x);
}

// ------- degree histogram: per-(bucket,chunk) partials, LDS atomics only
// blockIdx.y: 0 = row array, 1 = col array
__global__ __launch_bounds__(256) void hist_part_kernel(const int* __restrict__ row,
                                                        const int* __restrict__ col,
                                                        int* __restrict__ pr,
                                                        int* __restrict__ pc) {
    __shared__ int hh[BKT_SZ];
    int b = blockIdx.x / NCHK, c = blockIdx.x % NCHK;
    const int* arr = blockIdx.y ? col : row;
    int* out = blockIdx.y ? pc : pr;
    int tid = threadIdx.x;
    for (int i = tid; i < BKT_SZ; i += 256) hh[i] = 0;
    __syncthreads();
    int base = b * BKT_SZ;
    int e0 = c * CHK_E, e1 = e0 + CHK_E;
    for (int e = e0 + tid; e < e1; e += 256) {
        int uv = arr[e] - base;
        if ((unsigned)uv < BKT_SZ) atomicAdd(&hh[uv], 1);
    }
    __syncthreads();
    size_t ob = ((size_t)b * NCHK + c) * BKT_SZ;
    for (int i = tid; i < BKT_SZ; i += 256) out[ob + i] = hh[i];
}

// reduce partials -> degr/degc
__global__ __launch_bounds__(256) void hist_reduce_kernel(const int* __restrict__ pr,
                                                          const int* __restrict__ pc,
                                                          int* __restrict__ degr,
                                                          int* __restrict__ degc) {
    int n = blockIdx.x * 256 + threadIdx.x;
    if (n >= N_NODES) return;
    int b = n / BKT_SZ, off = n - b * BKT_SZ;
    size_t base = (size_t)b * NCHK * BKT_SZ + off;
    int sr = 0, sc = 0;
    for (int c = 0; c < NCHK; ++c) {
        size_t idx = base + (size_t)c * BKT_SZ;
        sr += pr[idx];
        sc += pc[idx];
    }
    degr[n] = sr;
    degc[n] = sc;
}

// ------------------------------------------------ hierarchical scan (3 kernels)
__global__ __launch_bounds__(256) void scan1_kernel(const int* __restrict__ degc,
                                                    int* __restrict__ csr_off,
                                                    int* __restrict__ blocksum) {
    __shared__ int buf[256];
    int tid = threadIdx.x;
    int i = blockIdx.x * 256 + tid;
    int v = (i < N_NODES) ? degc[i] : 0;
    buf[tid] = v;
    __syncthreads();
    for (int d = 1; d < 256; d <<= 1) {
        int t = (tid >= d) ? buf[tid - d] : 0;
        __syncthreads();
        buf[tid] += t;
        __syncthreads();
    }
    if (i < N_NODES) csr_off[i] = buf[tid] - v;
    if (tid == 255) blocksum[blockIdx.x] = buf[255];
}

__global__ __launch_bounds__(256) void scan2_kernel(int* __restrict__ blocksum) {
    __shared__ int buf[256];
    int tid = threadIdx.x;
    int v = (tid < SCAN_G) ? blocksum[tid] : 0;
    buf[tid] = v;
    __syncthreads();
    for (int d = 1; d < 256; d <<= 1) {
        int t = (tid >= d) ? buf[tid - d] : 0;
        __syncthreads();
        buf[tid] += t;
        __syncthreads();
    }
    if (tid < SCAN_G) blocksum[tid] = buf[tid] - v;   // exclusive, in place
}

__global__ __launch_bounds__(256) void scan3_kernel(const int* __restrict__ blocksum,
                                                    int* __restrict__ csr_off,
                                                    int* __restrict__ cursor) {
    int i = blockIdx.x * 256 + threadIdx.x;
    if (i < N_NODES) {
        int v = csr_off[i] + blocksum[blockIdx.x];
        csr_off[i] = v;
        cursor[i] = v;
    }
    if (i == 0) csr_off[N_NODES] = N_EDGES;
}

// --------------- counting-sort scatter via global atomic cursors
__global__ void fill_csr_kernel(const int* __restrict__ row, const int* __restrict__ col,
                                const int* __restrict__ degr, const int* __restrict__ degc,
                                int* __restrict__ cursor, int* __restrict__ row_off,
                                float2* __restrict__ pseudo_s) {
    int e = blockIdx.x * blockDim.x + threadIdx.x;
    if (e >= N_EDGES) return;
    int r = row[e], c = col[e];
    int pos = atomicAdd(&cursor[c], 1);
    row_off[pos] = r << 8;   // byte offset into fp16 h row (256 B)
    pseudo_s[pos] = make_float2(rsqrtf((float)degr[r] + 1.0f),
                                rsqrtf((float)degc[c] + 1.0f));
}

// ------------------------------- fp32 -> fp16 convert (vectorized)
__global__ void cvt16_kernel(const float4* __restrict__ src, half4v* __restrict__ dst, int n4) {
    int i = blockIdx.x * blockDim.x + threadIdx.x;
    if (i >= n4) return;
    float4 f = src[i];
    half4v o;
    o.x = (_Float16)f.x; o.y = (_Float16)f.y; o.z = (_Float16)f.z; o.w = (_Float16)f.w;
    dst[i] = o;
}

// ---------- fc_w transpose -> fp16: w2t[l][j][k*H+i] = fc_w[l][k*H+j][i]
__global__ void transpose_fc16_kernel(const float* __restrict__ fc_w,
                                      _Float16* __restrict__ w2t) {
    int idx = blockIdx.x * blockDim.x + threadIdx.x;
    if (idx >= NL * NK * HID * HID) return;
    int i = idx & (HID - 1);
    int j = (idx >> 7) & (HID - 1);
    int kl = idx >> 14;          // l*3 + k
    int k = kl % 3;
    int l = kl / 3;
    w2t[((size_t)(l * HID + j)) * (NK * HID) + k * HID + i] = (_Float16)fc_w[idx];
}

// -------------------------------------------------- fp16 MFMA GEMM
// C[M x 128] = A[M x Kd] @ W[128 x Kd]^T (+bias). 128x128 block tile.
// Optional fused BN stats; optional fp16 shadow of C.
__global__ __launch_bounds__(256) void gemm_f16_kernel(
        const _Float16* __restrict__ A, const _Float16* __restrict__ W,
        const float* __restrict__ bias, float* __restrict__ C, _Float16* __restrict__ C16,
        float* __restrict__ bnsum, int M, int Kd) {
    __shared__ _Float16 sA[128 * 40], sB[128 * 40];   // stride 40 halfs
    __shared__ float bsum[HID], bsq[HID];
    int tid = threadIdx.x;
    if (bnsum && tid < HID) { bsum[tid] = 0.f; bsq[tid] = 0.f; }
    int bm = blockIdx.x * 128;
    int wave = tid >> 6, lane = tid & 63;
    int ln = lane & 15, quad = lane >> 4;
    int wy = wave >> 1, wx = wave & 1;
    int srow = tid >> 2, scol = (tid & 3) << 3;
    floatx4 acc[4][4] = {};
    const half8 zv = {0, 0, 0, 0, 0, 0, 0, 0};

    half8 pA[2], pB[2];
    bool av0 = (bm + srow) < M, av1 = (bm + srow + 64) < M;
    const size_t aoff0 = (size_t)(bm + srow) * Kd + scol;
    const size_t aoff1 = (size_t)(bm + srow + 64) * Kd + scol;
    const size_t woff0 = (size_t)srow * Kd + scol;
    const size_t woff1 = (size_t)(srow + 64) * Kd + scol;

#define LOAD_TILE(K0)                                                          \
    do {                                                                       \
        pB[0] = *(const half8*)(W + woff0 + (K0));                             \
        pB[1] = *(const half8*)(W + woff1 + (K0));                             \
        pA[0] = av0 ? *(const half8*)(A + aoff0 + (K0)) : zv;                  \
        pA[1] = av1 ? *(const half8*)(A + aoff1 + (K0)) : zv;                  \
    } while (0)

    LOAD_TILE(0);
    for (int k0 = 0; k0 < Kd; k0 += 32) {
        __syncthreads();
#pragma unroll
        for (int rep = 0; rep < 2; ++rep) {
            int r = srow + rep * 64;
            *(half8*)&sA[r * 40 + scol] = pA[rep];
            *(half8*)&sB[r * 40 + scol] = pB[rep];
        }
        __syncthreads();
        if (k0 + 32 < Kd) LOAD_TILE(k0 + 32);   // overlaps with MFMA below
        half8 a[4], b[4];
        int kq = quad * 8;
#pragma unroll
        for (int i = 0; i < 4; ++i) {
            a[i] = *(const half8*)&sA[(wy * 64 + i * 16 + ln) * 40 + kq];
            b[i] = *(const half8*)&sB[(wx * 64 + i * 16 + ln) * 40 + kq];
        }
#pragma unroll
        for (int i = 0; i < 4; ++i)
#pragma unroll
            for (int j = 0; j < 4; ++j)
                acc[i][j] = __builtin_amdgcn_mfma_f32_16x16x32_f16(a[i], b[j], acc[i][j], 0, 0, 0);
    }
#undef LOAD_TILE

    // epilogue: C/D layout col = lane&15, row = quad*4 + reg
#pragma unroll
    for (int j = 0; j < 4; ++j) {
        int gc = wx * 64 + j * 16 + ln;
        float bv = bias ? bias[gc] : 0.f;
#pragma unroll
        for (int i = 0; i < 4; ++i) {
#pragma unroll
            for (int r = 0; r < 4; ++r) {
                int gr = bm + wy * 64 + i * 16 + quad * 4 + r;
                if (gr < M) {
                    float v = acc[i][j][r] + bv;
                    C[(size_t)gr * HID + gc] = v;
                    if (C16) C16[(size_t)gr * HID + gc] = (_Float16)v;
                }
            }
        }
    }
    if (bnsum) {
        // rows beyond M accumulated zeros (A loaded as 0, no bias) -> safe
#pragma unroll
        for (int j = 0; j < 4; ++j) {
            float s = 0.f, q = 0.f;
#pragma unroll
            for (int i = 0; i < 4; ++i)
#pragma unroll
                for (int r = 0; r < 4; ++r) { float v = acc[i][j][r]; s += v; q += v * v; }
            s += __shfl_xor(s, 16); s += __shfl_xor(s, 32);
            q += __shfl_xor(q, 16); q += __shfl_xor(q, 32);
            if (quad == 0) {
                atomicAdd(&bsum[wx * 64 + j * 16 + ln], s);
                atomicAdd(&bsq[wx * 64 + j * 16 + ln], q);
            }
        }
        __syncthreads();
        if (tid < HID) {
            atomicAdd(&bnsum[tid],       bsum[tid]);
            atomicAdd(&bnsum[HID + tid], bsq[tid]);
        }
    }
}

// ----------- CSR aggregation: fp16 h gather, inline edge-weight compute.
// Lane ce computes its edge's GMM weights wave-parallel from pseudo, then
// broadcasts (roff, w0, w1, w2) via shfl; 8 gathers in flight; pk_fma accum.
__global__ __launch_bounds__(256) void aggregate_kernel(const int* __restrict__ csr_off,
                                                        const int* __restrict__ row_off,
                                                        const float2* __restrict__ pseudo_s,
                                                        const float* __restrict__ pp_w,
                                                        const float* __restrict__ pp_b,
                                                        const float* __restrict__ mu,
                                                        const float* __restrict__ isig,
                                                        const char* __restrict__ h16,
                                                        _Float16* __restrict__ u) {
    int wave = threadIdx.x >> 6;
    int lane = threadIdx.x & 63;
    int n = blockIdx.x * 4 + wave;
    if (n >= N_NODES) return;
    // per-layer params (scalar, L2-resident)
    float pw0 = pp_w[0], pw1 = pp_w[1], pw2 = pp_w[2], pw3 = pp_w[3];
    float pb0 = pp_b[0], pb1 = pp_b[1];
    float mu00 = mu[0], mu01 = mu[1], mu10 = mu[2], mu11 = mu[3], mu20 = mu[4], mu21 = mu[5];
    float is00 = isig[0], is01 = isig[1], is10 = isig[2], is11 = isig[3], is20 = isig[4], is21 = isig[5];
    is00 *= is00; is01 *= is01; is10 *= is10; is11 *= is11; is20 *= is20; is21 *= is21;

    int beg = csr_off[n], end = csr_off[n + 1];
    const char* hb = h16 + lane * 4;
    float2v a0 = {0.f, 0.f}, a1 = {0.f, 0.f}, a2 = {0.f, 0.f};
    for (int chunk = beg; chunk < end; chunk += 64) {
        int ce = chunk + lane;
        int roff = 0;
        float w0 = 0.f, w1 = 0.f, w2 = 0.f;
        if (ce < end) {
            roff = row_off[ce];
            float2 p = pseudo_s[ce];
            float ps0 = tanh_fast(p.x * pw0 + p.y * pw1 + pb0);
            float ps1 = tanh_fast(p.x * pw2 + p.y * pw3 + pb1);
            float d00 = ps0 - mu00, d01 = ps1 - mu01;
            float d10 = ps0 - mu10, d11 = ps1 - mu11;
            float d20 = ps0 - mu20, d21 = ps1 - mu21;
            w0 = __expf(-0.5f * (d00 * d00 * is00 + d01 * d01 * is01));
            w1 = __expf(-0.5f * (d10 * d10 * is10 + d11 * d11 * is11));
            w2 = __expf(-0.5f * (d20 * d20 * is20 + d21 * d21 * is21));
        }
        int m = end - chunk; if (m > 64) m = 64;
        int t = 0;
        for (; t + 8 <= m; t += 8) {
            int ro[8];
#pragma unroll
            for (int s = 0; s < 8; ++s) ro[s] = __shfl(roff, t + s);
            half2v hv[8];
#pragma unroll
            for (int s = 0; s < 8; ++s) hv[s] = *(const half2v*)(hb + (unsigned)ro[s]);
            float wx[8], wy[8], wz[8];
#pragma unroll
            for (int s = 0; s < 8; ++s) {
                wx[s] = __shfl(w0, t + s);
                wy[s] = __shfl(w1, t + s);
                wz[s] = __shfl(w2, t + s);
            }
#pragma unroll
            for (int s = 0; s < 8; ++s) {
                float2v hf = {(float)hv[s].x, (float)hv[s].y};
                a0 += wx[s] * hf;
                a1 += wy[s] * hf;
                a2 += wz[s] * hf;
            }
        }
        for (; t < m; ++t) {
            int ro = __shfl(roff, t);
            float wx = __shfl(w0, t), wy = __shfl(w1, t), wz = __shfl(w2, t);
            half2v hv = *(const half2v*)(hb + (unsigned)ro);
            float2v hf = {(float)hv.x, (float)hv.y};
            a0 += wx * hf;
            a1 += wy * hf;
            a2 += wz * hf;
        }
    }
    size_t base = (size_t)n * 384 + lane * 2;
    half2v o0, o1, o2;
    o0.x = (_Float16)a0.x; o0.y = (_Float16)a0.y;
    o1.x = (_Float16)a1.x; o1.y = (_Float16)a1.y;
    o2.x = (_Float16)a2.x; o2.y = (_Float16)a2.y;
    *(half2v*)(u + base)       = o0;
    *(half2v*)(u + base + 128) = o1;
    *(half2v*)(u + base + 256) = o2;
}

// --------------------- BN apply + ReLU + residual (+ optional fp16 shadow)
__global__ void bn_apply_kernel(float4* __restrict__ h4, half4v* __restrict__ h16,
                                const float4* __restrict__ agg4,
                                const float* __restrict__ bnsum,
                                const float* __restrict__ gamma, const float* __restrict__ beta) {
    int idx = blockIdx.x * blockDim.x + threadIdx.x;
    if (idx >= N_NODES * HID / 4) return;
    int c = (idx & 31) * 4;
    const float invN = 1.0f / (float)N_NODES;
    float4 a = agg4[idx];
    float4 hv = h4[idx];
    float av[4] = {a.x, a.y, a.z, a.w};
    float hh[4] = {hv.x, hv.y, hv.z, hv.w};
    float o[4];
    half4v o16;
#pragma unroll
    for (int j = 0; j < 4; ++j) {
        float mean = bnsum[c + j] * invN;
        float var = bnsum[HID + c + j] * invN - mean * mean;
        float hn = (av[j] - mean) * rsqrtf(var + BN_EPS) * gamma[c + j] + beta[c + j];
        o[j] = hh[j] + fmaxf(hn, 0.f);
        o16[j] = (_Float16)o[j];
    }
    h4[idx] = make_float4(o[0], o[1], o[2], o[3]);
    if (h16) h16[idx] = o16;
}

// -------------------------------------------- fused readout + 3-layer MLP
__global__ __launch_bounds__(128) void readout_mlp_kernel(const float* __restrict__ h,
                                                          const int* __restrict__ batch,
                                                          const float* __restrict__ w0, const float* __restrict__ b0,
                                                          const float* __restrict__ w1, const float* __restrict__ b1,
                                                          const float* __restrict__ w2, const float* __restrict__ b2,
                                                          float* __restrict__ out) {
    __shared__ float hg[128];
    __shared__ float z0[64];
    __shared__ float z1[32];
    __shared__ int range[2];
    int g = blockIdx.x;
    int tid = threadIdx.x;
    if (tid == 0) {
        int lo = 0, hi = N_NODES;
        while (lo < hi) { int mid = (lo + hi) >> 1; if (batch[mid] < g) lo = mid + 1; else hi = mid; }
        range[0] = lo;
        hi = N_NODES;
        while (lo < hi) { int mid = (lo + hi) >> 1; if (batch[mid] < g + 1) lo = mid + 1; else hi = mid; }
        range[1] = lo;
    }
    __syncthreads();
    int lo = range[0], hi = range[1];
    float s0 = 0.f, s1 = 0.f, s2 = 0.f, s3 = 0.f;
    int n = lo;
    for (; n + 4 <= hi; n += 4) {
        s0 += h[(size_t)n * HID + tid];
        s1 += h[(size_t)(n + 1) * HID + tid];
        s2 += h[(size_t)(n + 2) * HID + tid];
        s3 += h[(size_t)(n + 3) * HID + tid];
    }
    for (; n < hi; ++n) s0 += h[(size_t)n * HID + tid];
    float s = (s0 + s1) + (s2 + s3);
    int cnt = hi - lo; if (cnt < 1) cnt = 1;
    hg[tid] = s / (float)cnt;
    __syncthreads();
    if (tid < 64) {
        float a = b0[tid];
        for (int i = 0; i < 128; ++i) a += hg[i] * w0[tid * 128 + i];
        z0[tid] = fmaxf(a, 0.f);
    }
    __syncthreads();
    if (tid < 32) {
        float a = b1[tid];
        for (int i = 0; i < 64; ++i) a += z0[i] * w1[tid * 64 + i];
        z1[tid] = fmaxf(a, 0.f);
    }
    __syncthreads();
    if (tid < 10) {
        float a = b2[tid];
        for (int i = 0; i < 32; ++i) a += z1[i] * w2[tid * 32 + i];
        out[g * NC + tid] = a;
    }
}

// ----------------------------------------------------------------- launch
extern "C" void kernel_launch(void* const* d_in, const int* in_sizes, int n_in,
                              void* d_out, int out_size, void* d_ws, size_t ws_size,
                              hipStream_t stream) {
    const float* feature = (const float*)d_in[0];
    const int*   edge    = (const int*)d_in[1];
    const int*   row     = edge;
    const int*   col     = edge + N_EDGES;
    const int*   batch   = (const int*)d_in[2];
    const float* emb_w   = (const float*)d_in[3];
    const float* emb_b   = (const float*)d_in[4];
    const float* fc_w    = (const float*)d_in[5];
    const float* mu      = (const float*)d_in[6];
    const float* isig    = (const float*)d_in[7];
    const float* gamma   = (const float*)d_in[8];
    const float* beta    = (const float*)d_in[9];
    const float* pp_w    = (const float*)d_in[10];
    const float* pp_b    = (const float*)d_in[11];
    const float* mw0     = (const float*)d_in[12];
    const float* mb0     = (const float*)d_in[13];
    const float* mw1     = (const float*)d_in[14];
    const float* mb1     = (const float*)d_in[15];
    const float* mw2     = (const float*)d_in[16];
    const float* mb2     = (const float*)d_in[17];
    float* out = (float*)d_out;

    // workspace carve-up (256B aligned)
    char* ws = (char*)d_ws;
    size_t off = 0;
    auto carve = [&](size_t bytes) { size_t o = off; off = (off + bytes + 255) & ~(size_t)255; return o; };
    float* h        = (float*)(ws + carve((size_t)N_NODES * HID * 4));
    _Float16* h16   = (_Float16*)(ws + carve((size_t)N_NODES * HID * 2));
    _Float16* u     = (_Float16*)(ws + carve((size_t)N_NODES * NK * HID * 2));
    float* agg      = (float*)(ws + carve((size_t)N_NODES * HID * 4));
    float2* pseudo_s= (float2*)(ws + carve((size_t)N_EDGES * 2 * 4));
    _Float16* w2t   = (_Float16*)(ws + carve((size_t)NL * HID * NK * HID * 2));
    _Float16* f16   = (_Float16*)(ws + carve((size_t)N_NODES * HID * 2));
    _Float16* e16   = (_Float16*)(ws + carve((size_t)HID * HID * 2));
    int* degr       = (int*)(ws + carve((size_t)N_NODES * 4));
    int* degc       = (int*)(ws + carve((size_t)N_NODES * 4));
    int* csr_off    = (int*)(ws + carve((size_t)(N_NODES + 1) * 4));
    int* cursor     = (int*)(ws + carve((size_t)N_NODES * 4));
    int* row_off    = (int*)(ws + carve((size_t)N_EDGES * 4));
    int* blocksum   = (int*)(ws + carve((size_t)SCAN_G * 4));
    int* pr         = (int*)(ws + carve((size_t)NBKT * NCHK * BKT_SZ * 4));
    int* pc         = (int*)(ws + carve((size_t)NBKT * NCHK * BKT_SZ * 4));
    float* bnsum    = (float*)(ws + carve((size_t)NL * 2 * HID * 4));
    (void)ws_size; (void)in_sizes; (void)n_in; (void)out_size;

    hipMemsetAsync(bnsum, 0, (size_t)NL * 2 * HID * 4, stream);

    hist_part_kernel<<<dim3(NBKT * NCHK, 2), 256, 0, stream>>>(row, col, pr, pc);
    hist_reduce_kernel<<<(N_NODES + 255) / 256, 256, 0, stream>>>(pr, pc, degr, degc);
    scan1_kernel<<<SCAN_G, 256, 0, stream>>>(degc, csr_off, blocksum);
    scan2_kernel<<<1, 256, 0, stream>>>(blocksum);
    scan3_kernel<<<SCAN_G, 256, 0, stream>>>(blocksum, csr_off, cursor);
    fill_csr_kernel<<<(N_EDGES + 255) / 256, 256, 0, stream>>>(row, col, degr, degc, cursor,
                                                               row_off, pseudo_s);

    cvt16_kernel<<<(N_NODES * HID / 4 + 255) / 256, 256, 0, stream>>>(
        (const float4*)feature, (half4v*)f16, N_NODES * HID / 4);
    cvt16_kernel<<<(HID * HID / 4 + 255) / 256, 256, 0, stream>>>(
        (const float4*)emb_w, (half4v*)e16, HID * HID / 4);
    transpose_fc16_kernel<<<(NL * NK * HID * HID + 255) / 256, 256, 0, stream>>>(fc_w, w2t);

    // h = feature @ emb_w^T + emb_b (fp32 h + fp16 shadow)
    gemm_f16_kernel<<<(N_NODES + 127) / 128, 256, 0, stream>>>(
        f16, e16, emb_b, h, h16, nullptr, N_NODES, HID);

    for (int l = 0; l < NL; ++l) {
        aggregate_kernel<<<(N_NODES + 3) / 4, 256, 0, stream>>>(
            csr_off, row_off, pseudo_s, pp_w + l * 4, pp_b + l * 2,
            mu + l * NK * 2, isig + l * NK * 2, (const char*)h16, u);
        gemm_f16_kernel<<<(N_NODES + 127) / 128, 256, 0, stream>>>(
            u, w2t + (size_t)l * HID * NK * HID, nullptr, agg, nullptr,
            bnsum + l * 2 * HID, N_NODES, NK * HID);
        bn_apply_kernel<<<(N_NODES * HID / 4 + 255) / 256, 256, 0, stream>>>(
            (float4*)h, (l < NL - 1) ? (half4v*)h16 : nullptr, (const float4*)agg,
            bnsum + l * 2 * HID, gamma + l * HID, beta + l * HID);
    }

    readout_mlp_kernel<<<N_GRAPHS, 128, 0, stream>>>(h, batch, mw0, mb0, mw1, mb1, mw2, mb2, out);
}

// Round 10
// 565.707 us; speedup vs baseline: 1.1321x; 1.0061x over previous
//
#include <hip/hip_runtime.h>
#include <hip/hip_bf16.h>

#define N_NODES 50000
#define N_EDGES 800000
#define N_GRAPHS 128
#define HID 128
#define NK 3
#define NL 4
#define NC 10
#define BN_EPS 1e-5f
#define SCAN_G ((N_NODES + 255) / 256)
#define NSLICE 32

// degree histogram bucketing
#define BKT_SZ 8192
#define NBKT 7                    // ceil(50000/8192)
#define NCHK 64
#define CHK_E (N_EDGES / NCHK)    // 12500

typedef __attribute__((ext_vector_type(8))) _Float16 half8;
typedef __attribute__((ext_vector_type(4))) float floatx4;
typedef __attribute__((ext_vector_type(2))) float float2v;
typedef __attribute__((ext_vector_type(2))) _Float16 half2v;
typedef __attribute__((ext_vector_type(4))) _Float16 half4v;

__device__ __forceinline__ float tanh_fast(float x) {
    float ax = fabsf(x);
    float t = __expf(-2.0f * ax);
    float r = (1.0f - t) / (1.0f + t);
    return copysignf(r, x);
}

// ------- degree histogram: per-(bucket,chunk) partials, LDS atomics only
__global__ __launch_bounds__(256) void hist_part_kernel(const int* __restrict__ row,
                                                        const int* __restrict__ col,
                                                        int* __restrict__ pr,
                                                        int* __restrict__ pc) {
    __shared__ int hh[BKT_SZ];
    int b = blockIdx.x / NCHK, c = blockIdx.x % NCHK;
    const int* arr = blockIdx.y ? col : row;
    int* out = blockIdx.y ? pc : pr;
    int tid = threadIdx.x;
    for (int i = tid; i < BKT_SZ; i += 256) hh[i] = 0;
    __syncthreads();
    int base = b * BKT_SZ;
    int e0 = c * CHK_E, e1 = e0 + CHK_E;
    for (int e = e0 + tid; e < e1; e += 256) {
        int uv = arr[e] - base;
        if ((unsigned)uv < BKT_SZ) atomicAdd(&hh[uv], 1);
    }
    __syncthreads();
    size_t ob = ((size_t)b * NCHK + c) * BKT_SZ;
    for (int i = tid; i < BKT_SZ; i += 256) out[ob + i] = hh[i];
}

// reduce partials -> degr/degc
__global__ __launch_bounds__(256) void hist_reduce_kernel(const int* __restrict__ pr,
                                                          const int* __restrict__ pc,
                                                          int* __restrict__ degr,
                                                          int* __restrict__ degc) {
    int n = blockIdx.x * 256 + threadIdx.x;
    if (n >= N_NODES) return;
    int b = n / BKT_SZ, off = n - b * BKT_SZ;
    size_t base = (size_t)b * NCHK * BKT_SZ + off;
    int sr = 0, sc = 0;
    for (int c = 0; c < NCHK; ++c) {
        size_t idx = base + (size_t)c * BKT_SZ;
        sr += pr[idx];
        sc += pc[idx];
    }
    degr[n] = sr;
    degc[n] = sc;
}

// ------------------------------------------------ hierarchical scan (3 kernels)
__global__ __launch_bounds__(256) void scan1_kernel(const int* __restrict__ degc,
                                                    int* __restrict__ csr_off,
                                                    int* __restrict__ blocksum) {
    __shared__ int buf[256];
    int tid = threadIdx.x;
    int i = blockIdx.x * 256 + tid;
    int v = (i < N_NODES) ? degc[i] : 0;
    buf[tid] = v;
    __syncthreads();
    for (int d = 1; d < 256; d <<= 1) {
        int t = (tid >= d) ? buf[tid - d] : 0;
        __syncthreads();
        buf[tid] += t;
        __syncthreads();
    }
    if (i < N_NODES) csr_off[i] = buf[tid] - v;
    if (tid == 255) blocksum[blockIdx.x] = buf[255];
}

__global__ __launch_bounds__(256) void scan2_kernel(int* __restrict__ blocksum) {
    __shared__ int buf[256];
    int tid = threadIdx.x;
    int v = (tid < SCAN_G) ? blocksum[tid] : 0;
    buf[tid] = v;
    __syncthreads();
    for (int d = 1; d < 256; d <<= 1) {
        int t = (tid >= d) ? buf[tid - d] : 0;
        __syncthreads();
        buf[tid] += t;
        __syncthreads();
    }
    if (tid < SCAN_G) blocksum[tid] = buf[tid] - v;   // exclusive, in place
}

__global__ __launch_bounds__(256) void scan3_kernel(const int* __restrict__ blocksum,
                                                    int* __restrict__ csr_off,
                                                    int* __restrict__ cursor) {
    int i = blockIdx.x * 256 + threadIdx.x;
    if (i < N_NODES) {
        int v = csr_off[i] + blocksum[blockIdx.x];
        csr_off[i] = v;
        cursor[i] = v;
    }
    if (i == 0) csr_off[N_NODES] = N_EDGES;
}

// --------------- counting-sort scatter: one 16-B EdgeRec per edge
// erec = { row_byte_off, pseudo.x, pseudo.y, 0 }
__global__ void fill_csr_kernel(const int* __restrict__ row, const int* __restrict__ col,
                                const int* __restrict__ degr, const int* __restrict__ degc,
                                int* __restrict__ cursor, int4* __restrict__ erec) {
    int e = blockIdx.x * blockDim.x + threadIdx.x;
    if (e >= N_EDGES) return;
    int r = row[e], c = col[e];
    int pos = atomicAdd(&cursor[c], 1);
    float px = rsqrtf((float)degr[r] + 1.0f);
    float py = rsqrtf((float)degc[c] + 1.0f);
    erec[pos] = make_int4(r << 8, __float_as_int(px), __float_as_int(py), 0);
}

// --------------------- fp32 -> fp16 convert (two sources, one dispatch)
__global__ void cvt16_dual_kernel(const float4* __restrict__ a, int n4a,
                                  const float4* __restrict__ b, int n4b,
                                  half4v* __restrict__ da, half4v* __restrict__ db) {
    int i = blockIdx.x * blockDim.x + threadIdx.x;
    const float4* src; half4v* dst; int idx;
    if (i < n4a) { src = a; dst = da; idx = i; }
    else if (i < n4a + n4b) { src = b; dst = db; idx = i - n4a; }
    else return;
    float4 f = src[idx];
    half4v o;
    o.x = (_Float16)f.x; o.y = (_Float16)f.y; o.z = (_Float16)f.z; o.w = (_Float16)f.w;
    dst[idx] = o;
}

// ---------- fc_w transpose -> fp16: w2t[l][j][k*H+i] = fc_w[l][k*H+j][i]
__global__ void transpose_fc16_kernel(const float* __restrict__ fc_w,
                                      _Float16* __restrict__ w2t) {
    int idx = blockIdx.x * blockDim.x + threadIdx.x;
    if (idx >= NL * NK * HID * HID) return;
    int i = idx & (HID - 1);
    int j = (idx >> 7) & (HID - 1);
    int kl = idx >> 14;          // l*3 + k
    int k = kl % 3;
    int l = kl / 3;
    w2t[((size_t)(l * HID + j)) * (NK * HID) + k * HID + i] = (_Float16)fc_w[idx];
}

// -------------------------------------------------- fp16 MFMA GEMM
// C[M x 128] = A[M x Kd] @ W[128 x Kd]^T (+bias). 128x128 block tile.
// BN stats (if bnsum) go to slice blockIdx&31 -> 32x less atomic contention.
__global__ __launch_bounds__(256) void gemm_f16_kernel(
        const _Float16* __restrict__ A, const _Float16* __restrict__ W,
        const float* __restrict__ bias, float* __restrict__ C, _Float16* __restrict__ C16,
        float* __restrict__ bnsum, int M, int Kd) {
    __shared__ _Float16 sA[128 * 40], sB[128 * 40];   // stride 40 halfs
    __shared__ float bsum[HID], bsq[HID];
    int tid = threadIdx.x;
    if (bnsum && tid < HID) { bsum[tid] = 0.f; bsq[tid] = 0.f; }
    int bm = blockIdx.x * 128;
    int wave = tid >> 6, lane = tid & 63;
    int ln = lane & 15, quad = lane >> 4;
    int wy = wave >> 1, wx = wave & 1;
    int srow = tid >> 2, scol = (tid & 3) << 3;
    floatx4 acc[4][4] = {};
    const half8 zv = {0, 0, 0, 0, 0, 0, 0, 0};

    half8 pA[2], pB[2];
    bool av0 = (bm + srow) < M, av1 = (bm + srow + 64) < M;
    const size_t aoff0 = (size_t)(bm + srow) * Kd + scol;
    const size_t aoff1 = (size_t)(bm + srow + 64) * Kd + scol;
    const size_t woff0 = (size_t)srow * Kd + scol;
    const size_t woff1 = (size_t)(srow + 64) * Kd + scol;

#define LOAD_TILE(K0)                                                          \
    do {                                                                       \
        pB[0] = *(const half8*)(W + woff0 + (K0));                             \
        pB[1] = *(const half8*)(W + woff1 + (K0));                             \
        pA[0] = av0 ? *(const half8*)(A + aoff0 + (K0)) : zv;                  \
        pA[1] = av1 ? *(const half8*)(A + aoff1 + (K0)) : zv;                  \
    } while (0)

    LOAD_TILE(0);
    for (int k0 = 0; k0 < Kd; k0 += 32) {
        __syncthreads();
#pragma unroll
        for (int rep = 0; rep < 2; ++rep) {
            int r = srow + rep * 64;
            *(half8*)&sA[r * 40 + scol] = pA[rep];
            *(half8*)&sB[r * 40 + scol] = pB[rep];
        }
        __syncthreads();
        if (k0 + 32 < Kd) LOAD_TILE(k0 + 32);   // overlaps with MFMA below
        half8 a[4], b[4];
        int kq = quad * 8;
#pragma unroll
        for (int i = 0; i < 4; ++i) {
            a[i] = *(const half8*)&sA[(wy * 64 + i * 16 + ln) * 40 + kq];
            b[i] = *(const half8*)&sB[(wx * 64 + i * 16 + ln) * 40 + kq];
        }
#pragma unroll
        for (int i = 0; i < 4; ++i)
#pragma unroll
            for (int j = 0; j < 4; ++j)
                acc[i][j] = __builtin_amdgcn_mfma_f32_16x16x32_f16(a[i], b[j], acc[i][j], 0, 0, 0);
    }
#undef LOAD_TILE

    // epilogue: C/D layout col = lane&15, row = quad*4 + reg
#pragma unroll
    for (int j = 0; j < 4; ++j) {
        int gc = wx * 64 + j * 16 + ln;
        float bv = bias ? bias[gc] : 0.f;
#pragma unroll
        for (int i = 0; i < 4; ++i) {
#pragma unroll
            for (int r = 0; r < 4; ++r) {
                int gr = bm + wy * 64 + i * 16 + quad * 4 + r;
                if (gr < M) {
                    float v = acc[i][j][r] + bv;
                    C[(size_t)gr * HID + gc] = v;
                    if (C16) C16[(size_t)gr * HID + gc] = (_Float16)v;
                }
            }
        }
    }
    if (bnsum) {
        // rows beyond M accumulated zeros (A loaded as 0, no bias) -> safe
#pragma unroll
        for (int j = 0; j < 4; ++j) {
            float s = 0.f, q = 0.f;
#pragma unroll
            for (int i = 0; i < 4; ++i)
#pragma unroll
                for (int r = 0; r < 4; ++r) { float v = acc[i][j][r]; s += v; q += v * v; }
            s += __shfl_xor(s, 16); s += __shfl_xor(s, 32);
            q += __shfl_xor(q, 16); q += __shfl_xor(q, 32);
            if (quad == 0) {
                atomicAdd(&bsum[wx * 64 + j * 16 + ln], s);
                atomicAdd(&bsq[wx * 64 + j * 16 + ln], q);
            }
        }
        __syncthreads();
        float* slice = bnsum + (blockIdx.x & (NSLICE - 1)) * (2 * HID);
        if (tid < HID) {
            atomicAdd(&slice[tid],       bsum[tid]);
            atomicAdd(&slice[HID + tid], bsq[tid]);
        }
    }
}

// ---- reduce BN slices -> fused scale/shift (one tiny block per layer)
__global__ __launch_bounds__(128) void bn_finalize_kernel(const float* __restrict__ slices,
                                                          const float* __restrict__ gamma,
                                                          const float* __restrict__ beta,
                                                          float* __restrict__ sc_sh) {
    int t = threadIdx.x;   // channel
    float s = 0.f, q = 0.f;
    for (int sl = 0; sl < NSLICE; ++sl) {
        s += slices[sl * (2 * HID) + t];
        q += slices[sl * (2 * HID) + HID + t];
    }
    const float invN = 1.0f / (float)N_NODES;
    float mean = s * invN;
    float var = q * invN - mean * mean;
    float scale = gamma[t] * rsqrtf(var + BN_EPS);
    sc_sh[t] = scale;
    sc_sh[HID + t] = beta[t] - mean * scale;
}

// ----------- CSR aggregation: fp16 h gather, inline edge-weight compute.
// Metadata = one int4/edge; 16 gathers in flight; pk_fma accumulate.
__global__ __launch_bounds__(256) void aggregate_kernel(const int* __restrict__ csr_off,
                                                        const int4* __restrict__ erec,
                                                        const float* __restrict__ pp_w,
                                                        const float* __restrict__ pp_b,
                                                        const float* __restrict__ mu,
                                                        const float* __restrict__ isig,
                                                        const char* __restrict__ h16,
                                                        _Float16* __restrict__ u) {
    int wave = threadIdx.x >> 6;
    int lane = threadIdx.x & 63;
    int n = blockIdx.x * 4 + wave;
    if (n >= N_NODES) return;
    float pw0 = pp_w[0], pw1 = pp_w[1], pw2 = pp_w[2], pw3 = pp_w[3];
    float pb0 = pp_b[0], pb1 = pp_b[1];
    float mu00 = mu[0], mu01 = mu[1], mu10 = mu[2], mu11 = mu[3], mu20 = mu[4], mu21 = mu[5];
    float is00 = isig[0], is01 = isig[1], is10 = isig[2], is11 = isig[3], is20 = isig[4], is21 = isig[5];
    is00 *= is00; is01 *= is01; is10 *= is10; is11 *= is11; is20 *= is20; is21 *= is21;

    int beg = csr_off[n], end = csr_off[n + 1];
    const char* hb = h16 + lane * 4;
    float2v a0 = {0.f, 0.f}, a1 = {0.f, 0.f}, a2 = {0.f, 0.f};
    for (int chunk = beg; chunk < end; chunk += 64) {
        int ce = chunk + lane;
        int roff = 0;
        float w0 = 0.f, w1 = 0.f, w2 = 0.f;
        if (ce < end) {
            int4 md = erec[ce];
            roff = md.x;
            float px = __int_as_float(md.y), py = __int_as_float(md.z);
            float ps0 = tanh_fast(px * pw0 + py * pw1 + pb0);
            float ps1 = tanh_fast(px * pw2 + py * pw3 + pb1);
            float d00 = ps0 - mu00, d01 = ps1 - mu01;
            float d10 = ps0 - mu10, d11 = ps1 - mu11;
            float d20 = ps0 - mu20, d21 = ps1 - mu21;
            w0 = __expf(-0.5f * (d00 * d00 * is00 + d01 * d01 * is01));
            w1 = __expf(-0.5f * (d10 * d10 * is10 + d11 * d11 * is11));
            w2 = __expf(-0.5f * (d20 * d20 * is20 + d21 * d21 * is21));
        }
        int m = end - chunk; if (m > 64) m = 64;
        int t = 0;
        for (; t + 16 <= m; t += 16) {
            int ro[16];
#pragma unroll
            for (int s = 0; s < 16; ++s) ro[s] = __shfl(roff, t + s);
            half2v hv[16];
#pragma unroll
            for (int s = 0; s < 16; ++s) hv[s] = *(const half2v*)(hb + (unsigned)ro[s]);
#pragma unroll
            for (int g = 0; g < 4; ++g) {
                float wx[4], wy[4], wz[4];
#pragma unroll
                for (int s = 0; s < 4; ++s) {
                    wx[s] = __shfl(w0, t + g * 4 + s);
                    wy[s] = __shfl(w1, t + g * 4 + s);
                    wz[s] = __shfl(w2, t + g * 4 + s);
                }
#pragma unroll
                for (int s = 0; s < 4; ++s) {
                    half2v hh = hv[g * 4 + s];
                    float2v hf = {(float)hh.x, (float)hh.y};
                    a0 += wx[s] * hf;
                    a1 += wy[s] * hf;
                    a2 += wz[s] * hf;
                }
            }
        }
        for (; t + 8 <= m; t += 8) {
            int ro[8];
#pragma unroll
            for (int s = 0; s < 8; ++s) ro[s] = __shfl(roff, t + s);
            half2v hv[8];
#pragma unroll
            for (int s = 0; s < 8; ++s) hv[s] = *(const half2v*)(hb + (unsigned)ro[s]);
            float wx[8], wy[8], wz[8];
#pragma unroll
            for (int s = 0; s < 8; ++s) {
                wx[s] = __shfl(w0, t + s);
                wy[s] = __shfl(w1, t + s);
                wz[s] = __shfl(w2, t + s);
            }
#pragma unroll
            for (int s = 0; s < 8; ++s) {
                float2v hf = {(float)hv[s].x, (float)hv[s].y};
                a0 += wx[s] * hf;
                a1 += wy[s] * hf;
                a2 += wz[s] * hf;
            }
        }
        for (; t < m; ++t) {
            int ro = __shfl(roff, t);
            float wx = __shfl(w0, t), wy = __shfl(w1, t), wz = __shfl(w2, t);
            half2v hv = *(const half2v*)(hb + (unsigned)ro);
            float2v hf = {(float)hv.x, (float)hv.y};
            a0 += wx * hf;
            a1 += wy * hf;
            a2 += wz * hf;
        }
    }
    size_t base = (size_t)n * 384 + lane * 2;
    half2v o0, o1, o2;
    o0.x = (_Float16)a0.x; o0.y = (_Float16)a0.y;
    o1.x = (_Float16)a1.x; o1.y = (_Float16)a1.y;
    o2.x = (_Float16)a2.x; o2.y = (_Float16)a2.y;
    *(half2v*)(u + base)       = o0;
    *(half2v*)(u + base + 128) = o1;
    *(half2v*)(u + base + 256) = o2;
}

// --------------------- BN apply (fused scale/shift) + ReLU + residual
__global__ void bn_apply_kernel(float4* __restrict__ h4, half4v* __restrict__ h16,
                                const float4* __restrict__ agg4,
                                const float* __restrict__ sc_sh) {
    int idx = blockIdx.x * blockDim.x + threadIdx.x;
    if (idx >= N_NODES * HID / 4) return;
    int c = (idx & 31) * 4;
    float4 a = agg4[idx];
    float4 hv = h4[idx];
    float av[4] = {a.x, a.y, a.z, a.w};
    float hh[4] = {hv.x, hv.y, hv.z, hv.w};
    float o[4];
    half4v o16;
#pragma unroll
    for (int j = 0; j < 4; ++j) {
        float hn = av[j] * sc_sh[c + j] + sc_sh[HID + c + j];
        o[j] = hh[j] + fmaxf(hn, 0.f);
        o16[j] = (_Float16)o[j];
    }
    h4[idx] = make_float4(o[0], o[1], o[2], o[3]);
    if (h16) h16[idx] = o16;
}

// -------------------------------------------- fused readout + 3-layer MLP
__global__ __launch_bounds__(128) void readout_mlp_kernel(const float* __restrict__ h,
                                                          const int* __restrict__ batch,
                                                          const float* __restrict__ w0, const float* __restrict__ b0,
                                                          const float* __restrict__ w1, const float* __restrict__ b1,
                                                          const float* __restrict__ w2, const float* __restrict__ b2,
                                                          float* __restrict__ out) {
    __shared__ float hg[128];
    __shared__ float z0[64];
    __shared__ float z1[32];
    __shared__ int range[2];
    int g = blockIdx.x;
    int tid = threadIdx.x;
    if (tid == 0) {
        int lo = 0, hi = N_NODES;
        while (lo < hi) { int mid = (lo + hi) >> 1; if (batch[mid] < g) lo = mid + 1; else hi = mid; }
        range[0] = lo;
        hi = N_NODES;
        while (lo < hi) { int mid = (lo + hi) >> 1; if (batch[mid] < g + 1) lo = mid + 1; else hi = mid; }
        range[1] = lo;
    }
    __syncthreads();
    int lo = range[0], hi = range[1];
    float s0 = 0.f, s1 = 0.f, s2 = 0.f, s3 = 0.f;
    int n = lo;
    for (; n + 4 <= hi; n += 4) {
        s0 += h[(size_t)n * HID + tid];
        s1 += h[(size_t)(n + 1) * HID + tid];
        s2 += h[(size_t)(n + 2) * HID + tid];
        s3 += h[(size_t)(n + 3) * HID + tid];
    }
    for (; n < hi; ++n) s0 += h[(size_t)n * HID + tid];
    float s = (s0 + s1) + (s2 + s3);
    int cnt = hi - lo; if (cnt < 1) cnt = 1;
    hg[tid] = s / (float)cnt;
    __syncthreads();
    if (tid < 64) {
        float a = b0[tid];
        for (int i = 0; i < 128; ++i) a += hg[i] * w0[tid * 128 + i];
        z0[tid] = fmaxf(a, 0.f);
    }
    __syncthreads();
    if (tid < 32) {
        float a = b1[tid];
        for (int i = 0; i < 64; ++i) a += z0[i] * w1[tid * 64 + i];
        z1[tid] = fmaxf(a, 0.f);
    }
    __syncthreads();
    if (tid < 10) {
        float a = b2[tid];
        for (int i = 0; i < 32; ++i) a += z1[i] * w2[tid * 32 + i];
        out[g * NC + tid] = a;
    }
}

// ----------------------------------------------------------------- launch
extern "C" void kernel_launch(void* const* d_in, const int* in_sizes, int n_in,
                              void* d_out, int out_size, void* d_ws, size_t ws_size,
                              hipStream_t stream) {
    const float* feature = (const float*)d_in[0];
    const int*   edge    = (const int*)d_in[1];
    const int*   row     = edge;
    const int*   col     = edge + N_EDGES;
    const int*   batch   = (const int*)d_in[2];
    const float* emb_w   = (const float*)d_in[3];
    const float* emb_b   = (const float*)d_in[4];
    const float* fc_w    = (const float*)d_in[5];
    const float* mu      = (const float*)d_in[6];
    const float* isig    = (const float*)d_in[7];
    const float* gamma   = (const float*)d_in[8];
    const float* beta    = (const float*)d_in[9];
    const float* pp_w    = (const float*)d_in[10];
    const float* pp_b    = (const float*)d_in[11];
    const float* mw0     = (const float*)d_in[12];
    const float* mb0     = (const float*)d_in[13];
    const float* mw1     = (const float*)d_in[14];
    const float* mb1     = (const float*)d_in[15];
    const float* mw2     = (const float*)d_in[16];
    const float* mb2     = (const float*)d_in[17];
    float* out = (float*)d_out;

    // workspace carve-up (256B aligned)
    char* ws = (char*)d_ws;
    size_t off = 0;
    auto carve = [&](size_t bytes) { size_t o = off; off = (off + bytes + 255) & ~(size_t)255; return o; };
    float* h        = (float*)(ws + carve((size_t)N_NODES * HID * 4));
    _Float16* h16   = (_Float16*)(ws + carve((size_t)N_NODES * HID * 2));
    _Float16* u     = (_Float16*)(ws + carve((size_t)N_NODES * NK * HID * 2));
    float* agg      = (float*)(ws + carve((size_t)N_NODES * HID * 4));
    int4* erec      = (int4*)(ws + carve((size_t)N_EDGES * 16));
    _Float16* w2t   = (_Float16*)(ws + carve((size_t)NL * HID * NK * HID * 2));
    _Float16* f16   = (_Float16*)(ws + carve((size_t)N_NODES * HID * 2));
    _Float16* e16   = (_Float16*)(ws + carve((size_t)HID * HID * 2));
    int* degr       = (int*)(ws + carve((size_t)N_NODES * 4));
    int* degc       = (int*)(ws + carve((size_t)N_NODES * 4));
    int* csr_off    = (int*)(ws + carve((size_t)(N_NODES + 1) * 4));
    int* cursor     = (int*)(ws + carve((size_t)N_NODES * 4));
    int* blocksum   = (int*)(ws + carve((size_t)SCAN_G * 4));
    int* pr         = (int*)(ws + carve((size_t)NBKT * NCHK * BKT_SZ * 4));
    int* pc         = (int*)(ws + carve((size_t)NBKT * NCHK * BKT_SZ * 4));
    float* bnsum    = (float*)(ws + carve((size_t)NL * NSLICE * 2 * HID * 4));
    float* bnfin    = (float*)(ws + carve((size_t)NL * 2 * HID * 4));
    (void)ws_size; (void)in_sizes; (void)n_in; (void)out_size;

    hipMemsetAsync(bnsum, 0, (size_t)NL * NSLICE * 2 * HID * 4, stream);

    hist_part_kernel<<<dim3(NBKT * NCHK, 2), 256, 0, stream>>>(row, col, pr, pc);
    hist_reduce_kernel<<<(N_NODES + 255) / 256, 256, 0, stream>>>(pr, pc, degr, degc);
    scan1_kernel<<<SCAN_G, 256, 0, stream>>>(degc, csr_off, blocksum);
    scan2_kernel<<<1, 256, 0, stream>>>(blocksum);
    scan3_kernel<<<SCAN_G, 256, 0, stream>>>(blocksum, csr_off, cursor);
    fill_csr_kernel<<<(N_EDGES + 255) / 256, 256, 0, stream>>>(row, col, degr, degc, cursor, erec);

    cvt16_dual_kernel<<<((N_NODES * HID + HID * HID) / 4 + 255) / 256, 256, 0, stream>>>(
        (const float4*)feature, N_NODES * HID / 4, (const float4*)emb_w, HID * HID / 4,
        (half4v*)f16, (half4v*)e16);
    transpose_fc16_kernel<<<(NL * NK * HID * HID + 255) / 256, 256, 0, stream>>>(fc_w, w2t);

    // h = feature @ emb_w^T + emb_b (fp32 h + fp16 shadow)
    gemm_f16_kernel<<<(N_NODES + 127) / 128, 256, 0, stream>>>(
        f16, e16, emb_b, h, h16, nullptr, N_NODES, HID);

    for (int l = 0; l < NL; ++l) {
        aggregate_kernel<<<(N_NODES + 3) / 4, 256, 0, stream>>>(
            csr_off, erec, pp_w + l * 4, pp_b + l * 2,
            mu + l * NK * 2, isig + l * NK * 2, (const char*)h16, u);
        gemm_f16_kernel<<<(N_NODES + 127) / 128, 256, 0, stream>>>(
            u, w2t + (size_t)l * HID * NK * HID, nullptr, agg, nullptr,
            bnsum + (size_t)l * NSLICE * 2 * HID, N_NODES, NK * HID);
        bn_finalize_kernel<<<1, 128, 0, stream>>>(
            bnsum + (size_t)l * NSLICE * 2 * HID, gamma + l * HID, beta + l * HID,
            bnfin + l * 2 * HID);
        bn_apply_kernel<<<(N_NODES * HID / 4 + 255) / 256, 256, 0, stream>>>(
            (float4*)h, (l < NL - 1) ? (half4v*)h16 : nullptr, (const float4*)agg,
            bnfin + l * 2 * HID);
    }

    readout_mlp_kernel<<<N_GRAPHS, 128, 0, stream>>>(h, batch, mw0, mb0, mw1, mb1, mw2, mb2, out);
}

// Round 11
// 561.755 us; speedup vs baseline: 1.1401x; 1.0070x over previous
//
#include <hip/hip_runtime.h>
#include <hip/hip_bf16.h>

#define N_NODES 50000
#define N_EDGES 800000
#define N_GRAPHS 128
#define HID 128
#define NK 3
#define NL 4
#define NC 10
#define BN_EPS 1e-5f
#define SCAN_G ((N_NODES + 255) / 256)
#define NSLICE 32

// degree histogram bucketing
#define BKT_SZ 8192
#define NBKT 7                    // ceil(50000/8192)
#define NCHK 64
#define CHK_E (N_EDGES / NCHK)    // 12500

typedef __attribute__((ext_vector_type(8))) _Float16 half8;
typedef __attribute__((ext_vector_type(4))) float floatx4;
typedef __attribute__((ext_vector_type(2))) float float2v;
typedef __attribute__((ext_vector_type(2))) _Float16 half2v;
typedef __attribute__((ext_vector_type(4))) _Float16 half4v;

__device__ __forceinline__ float tanh_fast(float x) {
    float ax = fabsf(x);
    float t = __expf(-2.0f * ax);
    float r = (1.0f - t) / (1.0f + t);
    return copysignf(r, x);
}

// ------- degree histogram: per-(bucket,chunk) partials, LDS atomics only
__global__ __launch_bounds__(256) void hist_part_kernel(const int* __restrict__ row,
                                                        const int* __restrict__ col,
                                                        int* __restrict__ pr,
                                                        int* __restrict__ pc) {
    __shared__ int hh[BKT_SZ];
    int b = blockIdx.x / NCHK, c = blockIdx.x % NCHK;
    const int* arr = blockIdx.y ? col : row;
    int* out = blockIdx.y ? pc : pr;
    int tid = threadIdx.x;
    for (int i = tid; i < BKT_SZ; i += 256) hh[i] = 0;
    __syncthreads();
    int base = b * BKT_SZ;
    int e0 = c * CHK_E, e1 = e0 + CHK_E;
    for (int e = e0 + tid; e < e1; e += 256) {
        int uv = arr[e] - base;
        if ((unsigned)uv < BKT_SZ) atomicAdd(&hh[uv], 1);
    }
    __syncthreads();
    size_t ob = ((size_t)b * NCHK + c) * BKT_SZ;
    for (int i = tid; i < BKT_SZ; i += 256) out[ob + i] = hh[i];
}

// reduce partials -> degr/degc
__global__ __launch_bounds__(256) void hist_reduce_kernel(const int* __restrict__ pr,
                                                          const int* __restrict__ pc,
                                                          int* __restrict__ degr,
                                                          int* __restrict__ degc) {
    int n = blockIdx.x * 256 + threadIdx.x;
    if (n >= N_NODES) return;
    int b = n / BKT_SZ, off = n - b * BKT_SZ;
    size_t base = (size_t)b * NCHK * BKT_SZ + off;
    int sr = 0, sc = 0;
    for (int c = 0; c < NCHK; ++c) {
        size_t idx = base + (size_t)c * BKT_SZ;
        sr += pr[idx];
        sc += pc[idx];
    }
    degr[n] = sr;
    degc[n] = sc;
}

// ------------------------------------------------ hierarchical scan (3 kernels)
__global__ __launch_bounds__(256) void scan1_kernel(const int* __restrict__ degc,
                                                    int* __restrict__ csr_off,
                                                    int* __restrict__ blocksum) {
    __shared__ int buf[256];
    int tid = threadIdx.x;
    int i = blockIdx.x * 256 + tid;
    int v = (i < N_NODES) ? degc[i] : 0;
    buf[tid] = v;
    __syncthreads();
    for (int d = 1; d < 256; d <<= 1) {
        int t = (tid >= d) ? buf[tid - d] : 0;
        __syncthreads();
        buf[tid] += t;
        __syncthreads();
    }
    if (i < N_NODES) csr_off[i] = buf[tid] - v;
    if (tid == 255) blocksum[blockIdx.x] = buf[255];
}

__global__ __launch_bounds__(256) void scan2_kernel(int* __restrict__ blocksum) {
    __shared__ int buf[256];
    int tid = threadIdx.x;
    int v = (tid < SCAN_G) ? blocksum[tid] : 0;
    buf[tid] = v;
    __syncthreads();
    for (int d = 1; d < 256; d <<= 1) {
        int t = (tid >= d) ? buf[tid - d] : 0;
        __syncthreads();
        buf[tid] += t;
        __syncthreads();
    }
    if (tid < SCAN_G) blocksum[tid] = buf[tid] - v;   // exclusive, in place
}

__global__ __launch_bounds__(256) void scan3_kernel(const int* __restrict__ blocksum,
                                                    int* __restrict__ csr_off,
                                                    int* __restrict__ cursor) {
    int i = blockIdx.x * 256 + threadIdx.x;
    if (i < N_NODES) {
        int v = csr_off[i] + blocksum[blockIdx.x];
        csr_off[i] = v;
        cursor[i] = v;
    }
    if (i == 0) csr_off[N_NODES] = N_EDGES;
}

// --------------- counting-sort scatter: one 16-B EdgeRec per edge
// erec = { row_byte_off, pseudo.x, pseudo.y, 0 }
__global__ void fill_csr_kernel(const int* __restrict__ row, const int* __restrict__ col,
                                const int* __restrict__ degr, const int* __restrict__ degc,
                                int* __restrict__ cursor, int4* __restrict__ erec) {
    int e = blockIdx.x * blockDim.x + threadIdx.x;
    if (e >= N_EDGES) return;
    int r = row[e], c = col[e];
    int pos = atomicAdd(&cursor[c], 1);
    float px = rsqrtf((float)degr[r] + 1.0f);
    float py = rsqrtf((float)degc[c] + 1.0f);
    erec[pos] = make_int4(r << 8, __float_as_int(px), __float_as_int(py), 0);
}

// ----- per-layer weight records: wrec[l][e] = {roff, w0, w1, w2} (fp32)
// coalesced read of erec, coalesced write; weight math hoisted out of aggregate
__global__ void edge_w_rec_kernel(const int4* __restrict__ erec,
                                  const float* __restrict__ pp_w, const float* __restrict__ pp_b,
                                  const float* __restrict__ mu, const float* __restrict__ isig,
                                  int4* __restrict__ wrec) {
    int e = blockIdx.x * blockDim.x + threadIdx.x;
    if (e >= N_EDGES) return;
    int4 md = erec[e];
    float px = __int_as_float(md.y), py = __int_as_float(md.z);
#pragma unroll
    for (int l = 0; l < NL; ++l) {
        float ps0 = tanh_fast(px * pp_w[l * 4 + 0] + py * pp_w[l * 4 + 1] + pp_b[l * 2 + 0]);
        float ps1 = tanh_fast(px * pp_w[l * 4 + 2] + py * pp_w[l * 4 + 3] + pp_b[l * 2 + 1]);
        float w[NK];
#pragma unroll
        for (int k = 0; k < NK; ++k) {
            float d0 = ps0 - mu[l * 6 + k * 2 + 0], d1 = ps1 - mu[l * 6 + k * 2 + 1];
            float s0 = isig[l * 6 + k * 2 + 0],     s1 = isig[l * 6 + k * 2 + 1];
            w[k] = __expf(-0.5f * (d0 * d0 * s0 * s0 + d1 * d1 * s1 * s1));
        }
        wrec[(size_t)l * N_EDGES + e] =
            make_int4(md.x, __float_as_int(w[0]), __float_as_int(w[1]), __float_as_int(w[2]));
    }
}

// --------------------- fp32 -> fp16 convert (two sources, one dispatch)
__global__ void cvt16_dual_kernel(const float4* __restrict__ a, int n4a,
                                  const float4* __restrict__ b, int n4b,
                                  half4v* __restrict__ da, half4v* __restrict__ db) {
    int i = blockIdx.x * blockDim.x + threadIdx.x;
    const float4* src; half4v* dst; int idx;
    if (i < n4a) { src = a; dst = da; idx = i; }
    else if (i < n4a + n4b) { src = b; dst = db; idx = i - n4a; }
    else return;
    float4 f = src[idx];
    half4v o;
    o.x = (_Float16)f.x; o.y = (_Float16)f.y; o.z = (_Float16)f.z; o.w = (_Float16)f.w;
    dst[idx] = o;
}

// ---------- fc_w transpose -> fp16: w2t[l][j][k*H+i] = fc_w[l][k*H+j][i]
__global__ void transpose_fc16_kernel(const float* __restrict__ fc_w,
                                      _Float16* __restrict__ w2t) {
    int idx = blockIdx.x * blockDim.x + threadIdx.x;
    if (idx >= NL * NK * HID * HID) return;
    int i = idx & (HID - 1);
    int j = (idx >> 7) & (HID - 1);
    int kl = idx >> 14;          // l*3 + k
    int k = kl % 3;
    int l = kl / 3;
    w2t[((size_t)(l * HID + j)) * (NK * HID) + k * HID + i] = (_Float16)fc_w[idx];
}

// -------------------------------------------------- fp16 MFMA GEMM
// C[M x 128] = A[M x Kd] @ W[128 x Kd]^T (+bias). 128x128 block tile.
// BN stats (if bnsum) go to slice blockIdx&31.
__global__ __launch_bounds__(256) void gemm_f16_kernel(
        const _Float16* __restrict__ A, const _Float16* __restrict__ W,
        const float* __restrict__ bias, float* __restrict__ C, _Float16* __restrict__ C16,
        float* __restrict__ bnsum, int M, int Kd) {
    __shared__ _Float16 sA[128 * 40], sB[128 * 40];   // stride 40 halfs
    __shared__ float bsum[HID], bsq[HID];
    int tid = threadIdx.x;
    if (bnsum && tid < HID) { bsum[tid] = 0.f; bsq[tid] = 0.f; }
    int bm = blockIdx.x * 128;
    int wave = tid >> 6, lane = tid & 63;
    int ln = lane & 15, quad = lane >> 4;
    int wy = wave >> 1, wx = wave & 1;
    int srow = tid >> 2, scol = (tid & 3) << 3;
    floatx4 acc[4][4] = {};
    const half8 zv = {0, 0, 0, 0, 0, 0, 0, 0};

    half8 pA[2], pB[2];
    bool av0 = (bm + srow) < M, av1 = (bm + srow + 64) < M;
    const size_t aoff0 = (size_t)(bm + srow) * Kd + scol;
    const size_t aoff1 = (size_t)(bm + srow + 64) * Kd + scol;
    const size_t woff0 = (size_t)srow * Kd + scol;
    const size_t woff1 = (size_t)(srow + 64) * Kd + scol;

#define LOAD_TILE(K0)                                                          \
    do {                                                                       \
        pB[0] = *(const half8*)(W + woff0 + (K0));                             \
        pB[1] = *(const half8*)(W + woff1 + (K0));                             \
        pA[0] = av0 ? *(const half8*)(A + aoff0 + (K0)) : zv;                  \
        pA[1] = av1 ? *(const half8*)(A + aoff1 + (K0)) : zv;                  \
    } while (0)

    LOAD_TILE(0);
    for (int k0 = 0; k0 < Kd; k0 += 32) {
        __syncthreads();
#pragma unroll
        for (int rep = 0; rep < 2; ++rep) {
            int r = srow + rep * 64;
            *(half8*)&sA[r * 40 + scol] = pA[rep];
            *(half8*)&sB[r * 40 + scol] = pB[rep];
        }
        __syncthreads();
        if (k0 + 32 < Kd) LOAD_TILE(k0 + 32);   // overlaps with MFMA below
        half8 a[4], b[4];
        int kq = quad * 8;
#pragma unroll
        for (int i = 0; i < 4; ++i) {
            a[i] = *(const half8*)&sA[(wy * 64 + i * 16 + ln) * 40 + kq];
            b[i] = *(const half8*)&sB[(wx * 64 + i * 16 + ln) * 40 + kq];
        }
#pragma unroll
        for (int i = 0; i < 4; ++i)
#pragma unroll
            for (int j = 0; j < 4; ++j)
                acc[i][j] = __builtin_amdgcn_mfma_f32_16x16x32_f16(a[i], b[j], acc[i][j], 0, 0, 0);
    }
#undef LOAD_TILE

    // epilogue: C/D layout col = lane&15, row = quad*4 + reg
#pragma unroll
    for (int j = 0; j < 4; ++j) {
        int gc = wx * 64 + j * 16 + ln;
        float bv = bias ? bias[gc] : 0.f;
#pragma unroll
        for (int i = 0; i < 4; ++i) {
#pragma unroll
            for (int r = 0; r < 4; ++r) {
                int gr = bm + wy * 64 + i * 16 + quad * 4 + r;
                if (gr < M) {
                    float v = acc[i][j][r] + bv;
                    C[(size_t)gr * HID + gc] = v;
                    if (C16) C16[(size_t)gr * HID + gc] = (_Float16)v;
                }
            }
        }
    }
    if (bnsum) {
        // rows beyond M accumulated zeros (A loaded as 0, no bias) -> safe
#pragma unroll
        for (int j = 0; j < 4; ++j) {
            float s = 0.f, q = 0.f;
#pragma unroll
            for (int i = 0; i < 4; ++i)
#pragma unroll
                for (int r = 0; r < 4; ++r) { float v = acc[i][j][r]; s += v; q += v * v; }
            s += __shfl_xor(s, 16); s += __shfl_xor(s, 32);
            q += __shfl_xor(q, 16); q += __shfl_xor(q, 32);
            if (quad == 0) {
                atomicAdd(&bsum[wx * 64 + j * 16 + ln], s);
                atomicAdd(&bsq[wx * 64 + j * 16 + ln], q);
            }
        }
        __syncthreads();
        float* slice = bnsum + (blockIdx.x & (NSLICE - 1)) * (2 * HID);
        if (tid < HID) {
            atomicAdd(&slice[tid],       bsum[tid]);
            atomicAdd(&slice[HID + tid], bsq[tid]);
        }
    }
}

// ---- reduce BN slices -> fused scale/shift (one tiny block per layer)
__global__ __launch_bounds__(128) void bn_finalize_kernel(const float* __restrict__ slices,
                                                          const float* __restrict__ gamma,
                                                          const float* __restrict__ beta,
                                                          float* __restrict__ sc_sh) {
    int t = threadIdx.x;   // channel
    float s = 0.f, q = 0.f;
    for (int sl = 0; sl < NSLICE; ++sl) {
        s += slices[sl * (2 * HID) + t];
        q += slices[sl * (2 * HID) + HID + t];
    }
    const float invN = 1.0f / (float)N_NODES;
    float mean = s * invN;
    float var = q * invN - mean * mean;
    float scale = gamma[t] * rsqrtf(var + BN_EPS);
    sc_sh[t] = scale;
    sc_sh[HID + t] = beta[t] - mean * scale;
}

// ----------- CSR aggregation: fp16 h gather, precomputed weight records.
// Per edge: 1 coalesced int4 load + 4 shfl + 1 gather + 2 cvt + 3 pk_fma.
__global__ __launch_bounds__(256) void aggregate_kernel(const int* __restrict__ csr_off,
                                                        const int4* __restrict__ wrec,
                                                        const char* __restrict__ h16,
                                                        _Float16* __restrict__ u) {
    int wave = threadIdx.x >> 6;
    int lane = threadIdx.x & 63;
    int n = blockIdx.x * 4 + wave;
    if (n >= N_NODES) return;
    int beg = csr_off[n], end = csr_off[n + 1];
    const char* hb = h16 + lane * 4;
    float2v a0 = {0.f, 0.f}, a1 = {0.f, 0.f}, a2 = {0.f, 0.f};
    for (int chunk = beg; chunk < end; chunk += 64) {
        int ce = chunk + lane;
        int roff = 0;
        float w0 = 0.f, w1 = 0.f, w2 = 0.f;
        if (ce < end) {
            int4 md = wrec[ce];
            roff = md.x;
            w0 = __int_as_float(md.y);
            w1 = __int_as_float(md.z);
            w2 = __int_as_float(md.w);
        }
        int m = end - chunk; if (m > 64) m = 64;
        int t = 0;
        for (; t + 16 <= m; t += 16) {
            int ro[16];
#pragma unroll
            for (int s = 0; s < 16; ++s) ro[s] = __shfl(roff, t + s);
            half2v hv[16];
#pragma unroll
            for (int s = 0; s < 16; ++s) hv[s] = *(const half2v*)(hb + (unsigned)ro[s]);
#pragma unroll
            for (int g = 0; g < 4; ++g) {
                float wx[4], wy[4], wz[4];
#pragma unroll
                for (int s = 0; s < 4; ++s) {
                    wx[s] = __shfl(w0, t + g * 4 + s);
                    wy[s] = __shfl(w1, t + g * 4 + s);
                    wz[s] = __shfl(w2, t + g * 4 + s);
                }
#pragma unroll
                for (int s = 0; s < 4; ++s) {
                    half2v hh = hv[g * 4 + s];
                    float2v hf = {(float)hh.x, (float)hh.y};
                    a0 += wx[s] * hf;
                    a1 += wy[s] * hf;
                    a2 += wz[s] * hf;
                }
            }
        }
        for (; t + 8 <= m; t += 8) {
            int ro[8];
#pragma unroll
            for (int s = 0; s < 8; ++s) ro[s] = __shfl(roff, t + s);
            half2v hv[8];
#pragma unroll
            for (int s = 0; s < 8; ++s) hv[s] = *(const half2v*)(hb + (unsigned)ro[s]);
            float wx[8], wy[8], wz[8];
#pragma unroll
            for (int s = 0; s < 8; ++s) {
                wx[s] = __shfl(w0, t + s);
                wy[s] = __shfl(w1, t + s);
                wz[s] = __shfl(w2, t + s);
            }
#pragma unroll
            for (int s = 0; s < 8; ++s) {
                float2v hf = {(float)hv[s].x, (float)hv[s].y};
                a0 += wx[s] * hf;
                a1 += wy[s] * hf;
                a2 += wz[s] * hf;
            }
        }
        for (; t < m; ++t) {
            int ro = __shfl(roff, t);
            float wx = __shfl(w0, t), wy = __shfl(w1, t), wz = __shfl(w2, t);
            half2v hv = *(const half2v*)(hb + (unsigned)ro);
            float2v hf = {(float)hv.x, (float)hv.y};
            a0 += wx * hf;
            a1 += wy * hf;
            a2 += wz * hf;
        }
    }
    size_t base = (size_t)n * 384 + lane * 2;
    half2v o0, o1, o2;
    o0.x = (_Float16)a0.x; o0.y = (_Float16)a0.y;
    o1.x = (_Float16)a1.x; o1.y = (_Float16)a1.y;
    o2.x = (_Float16)a2.x; o2.y = (_Float16)a2.y;
    *(half2v*)(u + base)       = o0;
    *(half2v*)(u + base + 128) = o1;
    *(half2v*)(u + base + 256) = o2;
}

// --------------------- BN apply (fused scale/shift) + ReLU + residual
__global__ void bn_apply_kernel(float4* __restrict__ h4, half4v* __restrict__ h16,
                                const float4* __restrict__ agg4,
                                const float* __restrict__ sc_sh) {
    int idx = blockIdx.x * blockDim.x + threadIdx.x;
    if (idx >= N_NODES * HID / 4) return;
    int c = (idx & 31) * 4;
    float4 a = agg4[idx];
    float4 hv = h4[idx];
    float av[4] = {a.x, a.y, a.z, a.w};
    float hh[4] = {hv.x, hv.y, hv.z, hv.w};
    float o[4];
    half4v o16;
#pragma unroll
    for (int j = 0; j < 4; ++j) {
        float hn = av[j] * sc_sh[c + j] + sc_sh[HID + c + j];
        o[j] = hh[j] + fmaxf(hn, 0.f);
        o16[j] = (_Float16)o[j];
    }
    h4[idx] = make_float4(o[0], o[1], o[2], o[3]);
    if (h16) h16[idx] = o16;
}

// -------------------------------------------- fused readout + 3-layer MLP
__global__ __launch_bounds__(128) void readout_mlp_kernel(const float* __restrict__ h,
                                                          const int* __restrict__ batch,
                                                          const float* __restrict__ w0, const float* __restrict__ b0,
                                                          const float* __restrict__ w1, const float* __restrict__ b1,
                                                          const float* __restrict__ w2, const float* __restrict__ b2,
                                                          float* __restrict__ out) {
    __shared__ float hg[128];
    __shared__ float z0[64];
    __shared__ float z1[32];
    __shared__ int range[2];
    int g = blockIdx.x;
    int tid = threadIdx.x;
    if (tid == 0) {
        int lo = 0, hi = N_NODES;
        while (lo < hi) { int mid = (lo + hi) >> 1; if (batch[mid] < g) lo = mid + 1; else hi = mid; }
        range[0] = lo;
        hi = N_NODES;
        while (lo < hi) { int mid = (lo + hi) >> 1; if (batch[mid] < g + 1) lo = mid + 1; else hi = mid; }
        range[1] = lo;
    }
    __syncthreads();
    int lo = range[0], hi = range[1];
    float s0 = 0.f, s1 = 0.f, s2 = 0.f, s3 = 0.f;
    int n = lo;
    for (; n + 4 <= hi; n += 4) {
        s0 += h[(size_t)n * HID + tid];
        s1 += h[(size_t)(n + 1) * HID + tid];
        s2 += h[(size_t)(n + 2) * HID + tid];
        s3 += h[(size_t)(n + 3) * HID + tid];
    }
    for (; n < hi; ++n) s0 += h[(size_t)n * HID + tid];
    float s = (s0 + s1) + (s2 + s3);
    int cnt = hi - lo; if (cnt < 1) cnt = 1;
    hg[tid] = s / (float)cnt;
    __syncthreads();
    if (tid < 64) {
        float a = b0[tid];
        for (int i = 0; i < 128; ++i) a += hg[i] * w0[tid * 128 + i];
        z0[tid] = fmaxf(a, 0.f);
    }
    __syncthreads();
    if (tid < 32) {
        float a = b1[tid];
        for (int i = 0; i < 64; ++i) a += z0[i] * w1[tid * 64 + i];
        z1[tid] = fmaxf(a, 0.f);
    }
    __syncthreads();
    if (tid < 10) {
        float a = b2[tid];
        for (int i = 0; i < 32; ++i) a += z1[i] * w2[tid * 32 + i];
        out[g * NC + tid] = a;
    }
}

// ----------------------------------------------------------------- launch
extern "C" void kernel_launch(void* const* d_in, const int* in_sizes, int n_in,
                              void* d_out, int out_size, void* d_ws, size_t ws_size,
                              hipStream_t stream) {
    const float* feature = (const float*)d_in[0];
    const int*   edge    = (const int*)d_in[1];
    const int*   row     = edge;
    const int*   col     = edge + N_EDGES;
    const int*   batch   = (const int*)d_in[2];
    const float* emb_w   = (const float*)d_in[3];
    const float* emb_b   = (const float*)d_in[4];
    const float* fc_w    = (const float*)d_in[5];
    const float* mu      = (const float*)d_in[6];
    const float* isig    = (const float*)d_in[7];
    const float* gamma   = (const float*)d_in[8];
    const float* beta    = (const float*)d_in[9];
    const float* pp_w    = (const float*)d_in[10];
    const float* pp_b    = (const float*)d_in[11];
    const float* mw0     = (const float*)d_in[12];
    const float* mb0     = (const float*)d_in[13];
    const float* mw1     = (const float*)d_in[14];
    const float* mb1     = (const float*)d_in[15];
    const float* mw2     = (const float*)d_in[16];
    const float* mb2     = (const float*)d_in[17];
    float* out = (float*)d_out;

    // workspace carve-up (256B aligned)
    char* ws = (char*)d_ws;
    size_t off = 0;
    auto carve = [&](size_t bytes) { size_t o = off; off = (off + bytes + 255) & ~(size_t)255; return o; };
    float* h        = (float*)(ws + carve((size_t)N_NODES * HID * 4));
    _Float16* h16   = (_Float16*)(ws + carve((size_t)N_NODES * HID * 2));
    _Float16* u     = (_Float16*)(ws + carve((size_t)N_NODES * NK * HID * 2));
    float* agg      = (float*)(ws + carve((size_t)N_NODES * HID * 4));
    int4* erec      = (int4*)(ws + carve((size_t)N_EDGES * 16));
    int4* wrec      = (int4*)(ws + carve((size_t)NL * N_EDGES * 16));
    _Float16* w2t   = (_Float16*)(ws + carve((size_t)NL * HID * NK * HID * 2));
    _Float16* f16   = (_Float16*)(ws + carve((size_t)N_NODES * HID * 2));
    _Float16* e16   = (_Float16*)(ws + carve((size_t)HID * HID * 2));
    int* degr       = (int*)(ws + carve((size_t)N_NODES * 4));
    int* degc       = (int*)(ws + carve((size_t)N_NODES * 4));
    int* csr_off    = (int*)(ws + carve((size_t)(N_NODES + 1) * 4));
    int* cursor     = (int*)(ws + carve((size_t)N_NODES * 4));
    int* blocksum   = (int*)(ws + carve((size_t)SCAN_G * 4));
    int* pr         = (int*)(ws + carve((size_t)NBKT * NCHK * BKT_SZ * 4));
    int* pc         = (int*)(ws + carve((size_t)NBKT * NCHK * BKT_SZ * 4));
    float* bnsum    = (float*)(ws + carve((size_t)NL * NSLICE * 2 * HID * 4));
    float* bnfin    = (float*)(ws + carve((size_t)NL * 2 * HID * 4));
    (void)ws_size; (void)in_sizes; (void)n_in; (void)out_size;

    hipMemsetAsync(bnsum, 0, (size_t)NL * NSLICE * 2 * HID * 4, stream);

    hist_part_kernel<<<dim3(NBKT * NCHK, 2), 256, 0, stream>>>(row, col, pr, pc);
    hist_reduce_kernel<<<(N_NODES + 255) / 256, 256, 0, stream>>>(pr, pc, degr, degc);
    scan1_kernel<<<SCAN_G, 256, 0, stream>>>(degc, csr_off, blocksum);
    scan2_kernel<<<1, 256, 0, stream>>>(blocksum);
    scan3_kernel<<<SCAN_G, 256, 0, stream>>>(blocksum, csr_off, cursor);
    fill_csr_kernel<<<(N_EDGES + 255) / 256, 256, 0, stream>>>(row, col, degr, degc, cursor, erec);
    edge_w_rec_kernel<<<(N_EDGES + 255) / 256, 256, 0, stream>>>(erec, pp_w, pp_b, mu, isig, wrec);

    cvt16_dual_kernel<<<((N_NODES * HID + HID * HID) / 4 + 255) / 256, 256, 0, stream>>>(
        (const float4*)feature, N_NODES * HID / 4, (const float4*)emb_w, HID * HID / 4,
        (half4v*)f16, (half4v*)e16);
    transpose_fc16_kernel<<<(NL * NK * HID * HID + 255) / 256, 256, 0, stream>>>(fc_w, w2t);

    // h = feature @ emb_w^T + emb_b (fp32 h + fp16 shadow)
    gemm_f16_kernel<<<(N_NODES + 127) / 128, 256, 0, stream>>>(
        f16, e16, emb_b, h, h16, nullptr, N_NODES, HID);

    for (int l = 0; l < NL; ++l) {
        aggregate_kernel<<<(N_NODES + 3) / 4, 256, 0, stream>>>(
            csr_off, wrec + (size_t)l * N_EDGES, (const char*)h16, u);
        gemm_f16_kernel<<<(N_NODES + 127) / 128, 256, 0, stream>>>(
            u, w2t + (size_t)l * HID * NK * HID, nullptr, agg, nullptr,
            bnsum + (size_t)l * NSLICE * 2 * HID, N_NODES, NK * HID);
        bn_finalize_kernel<<<1, 128, 0, stream>>>(
            bnsum + (size_t)l * NSLICE * 2 * HID, gamma + l * HID, beta + l * HID,
            bnfin + l * 2 * HID);
        bn_apply_kernel<<<(N_NODES * HID / 4 + 255) / 256, 256, 0, stream>>>(
            (float4*)h, (l < NL - 1) ? (half4v*)h16 : nullptr, (const float4*)agg,
            bnfin + l * 2 * HID);
    }

    readout_mlp_kernel<<<N_GRAPHS, 128, 0, stream>>>(h, batch, mw0, mb0, mw1, mb1, mw2, mb2, out);
}

// Round 12
// 559.034 us; speedup vs baseline: 1.1456x; 1.0049x over previous
//
#include <hip/hip_runtime.h>
#include <hip/hip_bf16.h>

#define N_NODES 50000
#define N_EDGES 800000
#define N_GRAPHS 128
#define HID 128
#define NK 3
#define NL 4
#define NC 10
#define BN_EPS 1e-5f
#define SCAN_G ((N_NODES + 255) / 256)
#define NSLICE 32

// degree histogram bucketing
#define BKT_SZ 8192
#define NBKT 7                    // ceil(50000/8192)
#define NCHK 64
#define CHK_E (N_EDGES / NCHK)    // 12500

typedef __attribute__((ext_vector_type(8))) _Float16 half8;
typedef __attribute__((ext_vector_type(4))) float floatx4;
typedef __attribute__((ext_vector_type(2))) float float2v;
typedef __attribute__((ext_vector_type(2))) _Float16 half2v;
typedef __attribute__((ext_vector_type(4))) _Float16 half4v;

__device__ __forceinline__ float tanh_fast(float x) {
    float ax = fabsf(x);
    float t = __expf(-2.0f * ax);
    float r = (1.0f - t) / (1.0f + t);
    return copysignf(r, x);
}

// ------- degree histogram: per-(bucket,chunk) partials, LDS atomics only
__global__ __launch_bounds__(256) void hist_part_kernel(const int* __restrict__ row,
                                                        const int* __restrict__ col,
                                                        int* __restrict__ pr,
                                                        int* __restrict__ pc) {
    __shared__ int hh[BKT_SZ];
    int b = blockIdx.x / NCHK, c = blockIdx.x % NCHK;
    const int* arr = blockIdx.y ? col : row;
    int* out = blockIdx.y ? pc : pr;
    int tid = threadIdx.x;
    for (int i = tid; i < BKT_SZ; i += 256) hh[i] = 0;
    __syncthreads();
    int base = b * BKT_SZ;
    int e0 = c * CHK_E, e1 = e0 + CHK_E;
    for (int e = e0 + tid; e < e1; e += 256) {
        int uv = arr[e] - base;
        if ((unsigned)uv < BKT_SZ) atomicAdd(&hh[uv], 1);
    }
    __syncthreads();
    size_t ob = ((size_t)b * NCHK + c) * BKT_SZ;
    for (int i = tid; i < BKT_SZ; i += 256) out[ob + i] = hh[i];
}

// reduce partials -> degr/degc
__global__ __launch_bounds__(256) void hist_reduce_kernel(const int* __restrict__ pr,
                                                          const int* __restrict__ pc,
                                                          int* __restrict__ degr,
                                                          int* __restrict__ degc) {
    int n = blockIdx.x * 256 + threadIdx.x;
    if (n >= N_NODES) return;
    int b = n / BKT_SZ, off = n - b * BKT_SZ;
    size_t base = (size_t)b * NCHK * BKT_SZ + off;
    int sr = 0, sc = 0;
    for (int c = 0; c < NCHK; ++c) {
        size_t idx = base + (size_t)c * BKT_SZ;
        sr += pr[idx];
        sc += pc[idx];
    }
    degr[n] = sr;
    degc[n] = sc;
}

// ------------------------------------------------ hierarchical scan (3 kernels)
__global__ __launch_bounds__(256) void scan1_kernel(const int* __restrict__ degc,
                                                    int* __restrict__ csr_off,
                                                    int* __restrict__ blocksum) {
    __shared__ int buf[256];
    int tid = threadIdx.x;
    int i = blockIdx.x * 256 + tid;
    int v = (i < N_NODES) ? degc[i] : 0;
    buf[tid] = v;
    __syncthreads();
    for (int d = 1; d < 256; d <<= 1) {
        int t = (tid >= d) ? buf[tid - d] : 0;
        __syncthreads();
        buf[tid] += t;
        __syncthreads();
    }
    if (i < N_NODES) csr_off[i] = buf[tid] - v;
    if (tid == 255) blocksum[blockIdx.x] = buf[255];
}

__global__ __launch_bounds__(256) void scan2_kernel(int* __restrict__ blocksum) {
    __shared__ int buf[256];
    int tid = threadIdx.x;
    int v = (tid < SCAN_G) ? blocksum[tid] : 0;
    buf[tid] = v;
    __syncthreads();
    for (int d = 1; d < 256; d <<= 1) {
        int t = (tid >= d) ? buf[tid - d] : 0;
        __syncthreads();
        buf[tid] += t;
        __syncthreads();
    }
    if (tid < SCAN_G) blocksum[tid] = buf[tid] - v;   // exclusive, in place
}

__global__ __launch_bounds__(256) void scan3_kernel(const int* __restrict__ blocksum,
                                                    int* __restrict__ csr_off,
                                                    int* __restrict__ cursor) {
    int i = blockIdx.x * 256 + threadIdx.x;
    if (i < N_NODES) {
        int v = csr_off[i] + blocksum[blockIdx.x];
        csr_off[i] = v;
        cursor[i] = v;
    }
    if (i == 0) csr_off[N_NODES] = N_EDGES;
}

// --------------- counting-sort scatter fused with per-layer GMM weights
// wrec[l][pos] = { row_byte_off, w0, w1, w2 } (fp32 bits)
__global__ void fill_csr_kernel(const int* __restrict__ row, const int* __restrict__ col,
                                const int* __restrict__ degr, const int* __restrict__ degc,
                                int* __restrict__ cursor,
                                const float* __restrict__ pp_w, const float* __restrict__ pp_b,
                                const float* __restrict__ mu, const float* __restrict__ isig,
                                int4* __restrict__ wrec) {
    int e = blockIdx.x * blockDim.x + threadIdx.x;
    if (e >= N_EDGES) return;
    int r = row[e], c = col[e];
    int pos = atomicAdd(&cursor[c], 1);
    float px = rsqrtf((float)degr[r] + 1.0f);
    float py = rsqrtf((float)degc[c] + 1.0f);
    int roff = r << 8;   // byte offset into fp16 h row (256 B)
#pragma unroll
    for (int l = 0; l < NL; ++l) {
        float ps0 = tanh_fast(px * pp_w[l * 4 + 0] + py * pp_w[l * 4 + 1] + pp_b[l * 2 + 0]);
        float ps1 = tanh_fast(px * pp_w[l * 4 + 2] + py * pp_w[l * 4 + 3] + pp_b[l * 2 + 1]);
        float w[NK];
#pragma unroll
        for (int k = 0; k < NK; ++k) {
            float d0 = ps0 - mu[l * 6 + k * 2 + 0], d1 = ps1 - mu[l * 6 + k * 2 + 1];
            float s0 = isig[l * 6 + k * 2 + 0],     s1 = isig[l * 6 + k * 2 + 1];
            w[k] = __expf(-0.5f * (d0 * d0 * s0 * s0 + d1 * d1 * s1 * s1));
        }
        wrec[(size_t)l * N_EDGES + pos] =
            make_int4(roff, __float_as_int(w[0]), __float_as_int(w[1]), __float_as_int(w[2]));
    }
}

// --------------------- fp32 -> fp16 convert (two sources, one dispatch)
__global__ void cvt16_dual_kernel(const float4* __restrict__ a, int n4a,
                                  const float4* __restrict__ b, int n4b,
                                  half4v* __restrict__ da, half4v* __restrict__ db) {
    int i = blockIdx.x * blockDim.x + threadIdx.x;
    const float4* src; half4v* dst; int idx;
    if (i < n4a) { src = a; dst = da; idx = i; }
    else if (i < n4a + n4b) { src = b; dst = db; idx = i - n4a; }
    else return;
    float4 f = src[idx];
    half4v o;
    o.x = (_Float16)f.x; o.y = (_Float16)f.y; o.z = (_Float16)f.z; o.w = (_Float16)f.w;
    dst[idx] = o;
}

// ---------- fc_w transpose -> fp16: w2t[l][j][k*H+i] = fc_w[l][k*H+j][i]
__global__ void transpose_fc16_kernel(const float* __restrict__ fc_w,
                                      _Float16* __restrict__ w2t) {
    int idx = blockIdx.x * blockDim.x + threadIdx.x;
    if (idx >= NL * NK * HID * HID) return;
    int i = idx & (HID - 1);
    int j = (idx >> 7) & (HID - 1);
    int kl = idx >> 14;          // l*3 + k
    int k = kl % 3;
    int l = kl / 3;
    w2t[((size_t)(l * HID + j)) * (NK * HID) + k * HID + i] = (_Float16)fc_w[idx];
}

// -------------------------------------------------- fp16 MFMA GEMM (split-N)
// C[M x 128] = A[M x Kd] @ W[128 x Kd]^T (+bias). Block: 128 rows x 64 cols,
// grid (ceil(M/128), 2) -> 782 blocks at M=50000 (~3/CU). Optional fp32 C,
// optional fp16 C16, optional BN stats into slice blockIdx.x&31.
__global__ __launch_bounds__(256) void gemm_f16_kernel(
        const _Float16* __restrict__ A, const _Float16* __restrict__ W,
        const float* __restrict__ bias, float* __restrict__ C, _Float16* __restrict__ C16,
        float* __restrict__ bnsum, int M, int Kd) {
    __shared__ _Float16 sA[128 * 40], sB[64 * 40];   // stride 40 halfs
    __shared__ float bsum[64], bsq[64];
    int tid = threadIdx.x;
    if (bnsum && tid < 64) { bsum[tid] = 0.f; bsq[tid] = 0.f; }
    int bm = blockIdx.x * 128;
    int bn = blockIdx.y * 64;
    int wave = tid >> 6, lane = tid & 63;
    int ln = lane & 15, quad = lane >> 4;
    int wy = wave >> 1, wx = wave & 1;
    int srow = tid >> 2, scol = (tid & 3) << 3;
    floatx4 acc[4][2] = {};
    const half8 zv = {0, 0, 0, 0, 0, 0, 0, 0};

    half8 pA[2], pB;
    bool av0 = (bm + srow) < M, av1 = (bm + srow + 64) < M;
    const size_t aoff0 = (size_t)(bm + srow) * Kd + scol;
    const size_t aoff1 = (size_t)(bm + srow + 64) * Kd + scol;
    const size_t woff  = (size_t)(bn + srow) * Kd + scol;

#define LOAD_TILE(K0)                                                          \
    do {                                                                       \
        pB = *(const half8*)(W + woff + (K0));                                 \
        pA[0] = av0 ? *(const half8*)(A + aoff0 + (K0)) : zv;                  \
        pA[1] = av1 ? *(const half8*)(A + aoff1 + (K0)) : zv;                  \
    } while (0)

    LOAD_TILE(0);
    for (int k0 = 0; k0 < Kd; k0 += 32) {
        __syncthreads();
        *(half8*)&sA[srow * 40 + scol] = pA[0];
        *(half8*)&sA[(srow + 64) * 40 + scol] = pA[1];
        *(half8*)&sB[srow * 40 + scol] = pB;
        __syncthreads();
        if (k0 + 32 < Kd) LOAD_TILE(k0 + 32);   // overlaps with MFMA below
        half8 a[4], b[2];
        int kq = quad * 8;
#pragma unroll
        for (int i = 0; i < 4; ++i)
            a[i] = *(const half8*)&sA[(wy * 64 + i * 16 + ln) * 40 + kq];
#pragma unroll
        for (int j = 0; j < 2; ++j)
            b[j] = *(const half8*)&sB[(wx * 32 + j * 16 + ln) * 40 + kq];
#pragma unroll
        for (int i = 0; i < 4; ++i)
#pragma unroll
            for (int j = 0; j < 2; ++j)
                acc[i][j] = __builtin_amdgcn_mfma_f32_16x16x32_f16(a[i], b[j], acc[i][j], 0, 0, 0);
    }
#undef LOAD_TILE

    // epilogue: C/D layout col = lane&15, row = quad*4 + reg
#pragma unroll
    for (int j = 0; j < 2; ++j) {
        int gc = bn + wx * 32 + j * 16 + ln;
        float bv = bias ? bias[gc] : 0.f;
#pragma unroll
        for (int i = 0; i < 4; ++i) {
#pragma unroll
            for (int r = 0; r < 4; ++r) {
                int gr = bm + wy * 64 + i * 16 + quad * 4 + r;
                if (gr < M) {
                    float v = acc[i][j][r] + bv;
                    if (C)   C[(size_t)gr * HID + gc] = v;
                    if (C16) C16[(size_t)gr * HID + gc] = (_Float16)v;
                }
            }
        }
    }
    if (bnsum) {
        // rows beyond M accumulated zeros (A loaded as 0, no bias) -> safe
#pragma unroll
        for (int j = 0; j < 2; ++j) {
            float s = 0.f, q = 0.f;
#pragma unroll
            for (int i = 0; i < 4; ++i)
#pragma unroll
                for (int r = 0; r < 4; ++r) { float v = acc[i][j][r]; s += v; q += v * v; }
            s += __shfl_xor(s, 16); s += __shfl_xor(s, 32);
            q += __shfl_xor(q, 16); q += __shfl_xor(q, 32);
            if (quad == 0) {
                atomicAdd(&bsum[wx * 32 + j * 16 + ln], s);
                atomicAdd(&bsq[wx * 32 + j * 16 + ln], q);
            }
        }
        __syncthreads();
        float* slice = bnsum + (blockIdx.x & (NSLICE - 1)) * (2 * HID);
        if (tid < 64) {
            atomicAdd(&slice[bn + tid],       bsum[tid]);
            atomicAdd(&slice[HID + bn + tid], bsq[tid]);
        }
    }
}

// ---- reduce BN slices -> fused scale/shift (one tiny block per layer)
__global__ __launch_bounds__(128) void bn_finalize_kernel(const float* __restrict__ slices,
                                                          const float* __restrict__ gamma,
                                                          const float* __restrict__ beta,
                                                          float* __restrict__ sc_sh) {
    int t = threadIdx.x;   // channel
    float s = 0.f, q = 0.f;
    for (int sl = 0; sl < NSLICE; ++sl) {
        s += slices[sl * (2 * HID) + t];
        q += slices[sl * (2 * HID) + HID + t];
    }
    const float invN = 1.0f / (float)N_NODES;
    float mean = s * invN;
    float var = q * invN - mean * mean;
    float scale = gamma[t] * rsqrtf(var + BN_EPS);
    sc_sh[t] = scale;
    sc_sh[HID + t] = beta[t] - mean * scale;
}

// ----------- CSR aggregation: fp16 h gather, precomputed weight records.
__global__ __launch_bounds__(256) void aggregate_kernel(const int* __restrict__ csr_off,
                                                        const int4* __restrict__ wrec,
                                                        const char* __restrict__ h16,
                                                        _Float16* __restrict__ u) {
    int wave = threadIdx.x >> 6;
    int lane = threadIdx.x & 63;
    int n = blockIdx.x * 4 + wave;
    if (n >= N_NODES) return;
    int beg = csr_off[n], end = csr_off[n + 1];
    const char* hb = h16 + lane * 4;
    float2v a0 = {0.f, 0.f}, a1 = {0.f, 0.f}, a2 = {0.f, 0.f};
    for (int chunk = beg; chunk < end; chunk += 64) {
        int ce = chunk + lane;
        int roff = 0;
        float w0 = 0.f, w1 = 0.f, w2 = 0.f;
        if (ce < end) {
            int4 md = wrec[ce];
            roff = md.x;
            w0 = __int_as_float(md.y);
            w1 = __int_as_float(md.z);
            w2 = __int_as_float(md.w);
        }
        int m = end - chunk; if (m > 64) m = 64;
        int t = 0;
        for (; t + 16 <= m; t += 16) {
            int ro[16];
#pragma unroll
            for (int s = 0; s < 16; ++s) ro[s] = __shfl(roff, t + s);
            half2v hv[16];
#pragma unroll
            for (int s = 0; s < 16; ++s) hv[s] = *(const half2v*)(hb + (unsigned)ro[s]);
#pragma unroll
            for (int g = 0; g < 4; ++g) {
                float wx[4], wy[4], wz[4];
#pragma unroll
                for (int s = 0; s < 4; ++s) {
                    wx[s] = __shfl(w0, t + g * 4 + s);
                    wy[s] = __shfl(w1, t + g * 4 + s);
                    wz[s] = __shfl(w2, t + g * 4 + s);
                }
#pragma unroll
                for (int s = 0; s < 4; ++s) {
                    half2v hh = hv[g * 4 + s];
                    float2v hf = {(float)hh.x, (float)hh.y};
                    a0 += wx[s] * hf;
                    a1 += wy[s] * hf;
                    a2 += wz[s] * hf;
                }
            }
        }
        for (; t + 8 <= m; t += 8) {
            int ro[8];
#pragma unroll
            for (int s = 0; s < 8; ++s) ro[s] = __shfl(roff, t + s);
            half2v hv[8];
#pragma unroll
            for (int s = 0; s < 8; ++s) hv[s] = *(const half2v*)(hb + (unsigned)ro[s]);
            float wx[8], wy[8], wz[8];
#pragma unroll
            for (int s = 0; s < 8; ++s) {
                wx[s] = __shfl(w0, t + s);
                wy[s] = __shfl(w1, t + s);
                wz[s] = __shfl(w2, t + s);
            }
#pragma unroll
            for (int s = 0; s < 8; ++s) {
                float2v hf = {(float)hv[s].x, (float)hv[s].y};
                a0 += wx[s] * hf;
                a1 += wy[s] * hf;
                a2 += wz[s] * hf;
            }
        }
        for (; t < m; ++t) {
            int ro = __shfl(roff, t);
            float wx = __shfl(w0, t), wy = __shfl(w1, t), wz = __shfl(w2, t);
            half2v hv = *(const half2v*)(hb + (unsigned)ro);
            float2v hf = {(float)hv.x, (float)hv.y};
            a0 += wx * hf;
            a1 += wy * hf;
            a2 += wz * hf;
        }
    }
    size_t base = (size_t)n * 384 + lane * 2;
    half2v o0, o1, o2;
    o0.x = (_Float16)a0.x; o0.y = (_Float16)a0.y;
    o1.x = (_Float16)a1.x; o1.y = (_Float16)a1.y;
    o2.x = (_Float16)a2.x; o2.y = (_Float16)a2.y;
    *(half2v*)(u + base)       = o0;
    *(half2v*)(u + base + 128) = o1;
    *(half2v*)(u + base + 256) = o2;
}

// ------- BN apply (fused scale/shift) + ReLU + residual; agg read as fp16
__global__ void bn_apply_kernel(float4* __restrict__ h4, half4v* __restrict__ h16,
                                const half4v* __restrict__ agg16,
                                const float* __restrict__ sc_sh) {
    int idx = blockIdx.x * blockDim.x + threadIdx.x;
    if (idx >= N_NODES * HID / 4) return;
    int c = (idx & 31) * 4;
    half4v a = agg16[idx];
    float4 hv = h4[idx];
    float av[4] = {(float)a.x, (float)a.y, (float)a.z, (float)a.w};
    float hh[4] = {hv.x, hv.y, hv.z, hv.w};
    float o[4];
    half4v o16;
#pragma unroll
    for (int j = 0; j < 4; ++j) {
        float hn = av[j] * sc_sh[c + j] + sc_sh[HID + c + j];
        o[j] = hh[j] + fmaxf(hn, 0.f);
        o16[j] = (_Float16)o[j];
    }
    h4[idx] = make_float4(o[0], o[1], o[2], o[3]);
    if (h16) h16[idx] = o16;
}

// -------------------------------------------- fused readout + 3-layer MLP
__global__ __launch_bounds__(128) void readout_mlp_kernel(const float* __restrict__ h,
                                                          const int* __restrict__ batch,
                                                          const float* __restrict__ w0, const float* __restrict__ b0,
                                                          const float* __restrict__ w1, const float* __restrict__ b1,
                                                          const float* __restrict__ w2, const float* __restrict__ b2,
                                                          float* __restrict__ out) {
    __shared__ float hg[128];
    __shared__ float z0[64];
    __shared__ float z1[32];
    __shared__ int range[2];
    int g = blockIdx.x;
    int tid = threadIdx.x;
    if (tid == 0) {
        int lo = 0, hi = N_NODES;
        while (lo < hi) { int mid = (lo + hi) >> 1; if (batch[mid] < g) lo = mid + 1; else hi = mid; }
        range[0] = lo;
        hi = N_NODES;
        while (lo < hi) { int mid = (lo + hi) >> 1; if (batch[mid] < g + 1) lo = mid + 1; else hi = mid; }
        range[1] = lo;
    }
    __syncthreads();
    int lo = range[0], hi = range[1];
    float s0 = 0.f, s1 = 0.f, s2 = 0.f, s3 = 0.f;
    int n = lo;
    for (; n + 4 <= hi; n += 4) {
        s0 += h[(size_t)n * HID + tid];
        s1 += h[(size_t)(n + 1) * HID + tid];
        s2 += h[(size_t)(n + 2) * HID + tid];
        s3 += h[(size_t)(n + 3) * HID + tid];
    }
    for (; n < hi; ++n) s0 += h[(size_t)n * HID + tid];
    float s = (s0 + s1) + (s2 + s3);
    int cnt = hi - lo; if (cnt < 1) cnt = 1;
    hg[tid] = s / (float)cnt;
    __syncthreads();
    if (tid < 64) {
        float a = b0[tid];
        for (int i = 0; i < 128; ++i) a += hg[i] * w0[tid * 128 + i];
        z0[tid] = fmaxf(a, 0.f);
    }
    __syncthreads();
    if (tid < 32) {
        float a = b1[tid];
        for (int i = 0; i < 64; ++i) a += z0[i] * w1[tid * 64 + i];
        z1[tid] = fmaxf(a, 0.f);
    }
    __syncthreads();
    if (tid < 10) {
        float a = b2[tid];
        for (int i = 0; i < 32; ++i) a += z1[i] * w2[tid * 32 + i];
        out[g * NC + tid] = a;
    }
}

// ----------------------------------------------------------------- launch
extern "C" void kernel_launch(void* const* d_in, const int* in_sizes, int n_in,
                              void* d_out, int out_size, void* d_ws, size_t ws_size,
                              hipStream_t stream) {
    const float* feature = (const float*)d_in[0];
    const int*   edge    = (const int*)d_in[1];
    const int*   row     = edge;
    const int*   col     = edge + N_EDGES;
    const int*   batch   = (const int*)d_in[2];
    const float* emb_w   = (const float*)d_in[3];
    const float* emb_b   = (const float*)d_in[4];
    const float* fc_w    = (const float*)d_in[5];
    const float* mu      = (const float*)d_in[6];
    const float* isig    = (const float*)d_in[7];
    const float* gamma   = (const float*)d_in[8];
    const float* beta    = (const float*)d_in[9];
    const float* pp_w    = (const float*)d_in[10];
    const float* pp_b    = (const float*)d_in[11];
    const float* mw0     = (const float*)d_in[12];
    const float* mb0     = (const float*)d_in[13];
    const float* mw1     = (const float*)d_in[14];
    const float* mb1     = (const float*)d_in[15];
    const float* mw2     = (const float*)d_in[16];
    const float* mb2     = (const float*)d_in[17];
    float* out = (float*)d_out;

    // workspace carve-up (256B aligned)
    char* ws = (char*)d_ws;
    size_t off = 0;
    auto carve = [&](size_t bytes) { size_t o = off; off = (off + bytes + 255) & ~(size_t)255; return o; };
    float* h        = (float*)(ws + carve((size_t)N_NODES * HID * 4));
    _Float16* h16   = (_Float16*)(ws + carve((size_t)N_NODES * HID * 2));
    _Float16* u     = (_Float16*)(ws + carve((size_t)N_NODES * NK * HID * 2));
    _Float16* agg16 = (_Float16*)(ws + carve((size_t)N_NODES * HID * 2));
    int4* wrec      = (int4*)(ws + carve((size_t)NL * N_EDGES * 16));
    _Float16* w2t   = (_Float16*)(ws + carve((size_t)NL * HID * NK * HID * 2));
    _Float16* f16   = (_Float16*)(ws + carve((size_t)N_NODES * HID * 2));
    _Float16* e16   = (_Float16*)(ws + carve((size_t)HID * HID * 2));
    int* degr       = (int*)(ws + carve((size_t)N_NODES * 4));
    int* degc       = (int*)(ws + carve((size_t)N_NODES * 4));
    int* csr_off    = (int*)(ws + carve((size_t)(N_NODES + 1) * 4));
    int* cursor     = (int*)(ws + carve((size_t)N_NODES * 4));
    int* blocksum   = (int*)(ws + carve((size_t)SCAN_G * 4));
    int* pr         = (int*)(ws + carve((size_t)NBKT * NCHK * BKT_SZ * 4));
    int* pc         = (int*)(ws + carve((size_t)NBKT * NCHK * BKT_SZ * 4));
    float* bnsum    = (float*)(ws + carve((size_t)NL * NSLICE * 2 * HID * 4));
    float* bnfin    = (float*)(ws + carve((size_t)NL * 2 * HID * 4));
    (void)ws_size; (void)in_sizes; (void)n_in; (void)out_size;

    hipMemsetAsync(bnsum, 0, (size_t)NL * NSLICE * 2 * HID * 4, stream);

    hist_part_kernel<<<dim3(NBKT * NCHK, 2), 256, 0, stream>>>(row, col, pr, pc);
    hist_reduce_kernel<<<(N_NODES + 255) / 256, 256, 0, stream>>>(pr, pc, degr, degc);
    scan1_kernel<<<SCAN_G, 256, 0, stream>>>(degc, csr_off, blocksum);
    scan2_kernel<<<1, 256, 0, stream>>>(blocksum);
    scan3_kernel<<<SCAN_G, 256, 0, stream>>>(blocksum, csr_off, cursor);
    fill_csr_kernel<<<(N_EDGES + 255) / 256, 256, 0, stream>>>(
        row, col, degr, degc, cursor, pp_w, pp_b, mu, isig, wrec);

    cvt16_dual_kernel<<<((N_NODES * HID + HID * HID) / 4 + 255) / 256, 256, 0, stream>>>(
        (const float4*)feature, N_NODES * HID / 4, (const float4*)emb_w, HID * HID / 4,
        (half4v*)f16, (half4v*)e16);
    transpose_fc16_kernel<<<(NL * NK * HID * HID + 255) / 256, 256, 0, stream>>>(fc_w, w2t);

    // h = feature @ emb_w^T + emb_b (fp32 h + fp16 shadow)
    gemm_f16_kernel<<<dim3((N_NODES + 127) / 128, 2), 256, 0, stream>>>(
        f16, e16, emb_b, h, h16, nullptr, N_NODES, HID);

    for (int l = 0; l < NL; ++l) {
        aggregate_kernel<<<(N_NODES + 3) / 4, 256, 0, stream>>>(
            csr_off, wrec + (size_t)l * N_EDGES, (const char*)h16, u);
        gemm_f16_kernel<<<dim3((N_NODES + 127) / 128, 2), 256, 0, stream>>>(
            u, w2t + (size_t)l * HID * NK * HID, nullptr, nullptr, agg16,
            bnsum + (size_t)l * NSLICE * 2 * HID, N_NODES, NK * HID);
        bn_finalize_kernel<<<1, 128, 0, stream>>>(
            bnsum + (size_t)l * NSLICE * 2 * HID, gamma + l * HID, beta + l * HID,
            bnfin + l * 2 * HID);
        bn_apply_kernel<<<(N_NODES * HID / 4 + 255) / 256, 256, 0, stream>>>(
            (float4*)h, (l < NL - 1) ? (half4v*)h16 : nullptr, (const half4v*)agg16,
            bnfin + l * 2 * HID);
    }

    readout_mlp_kernel<<<N_GRAPHS, 128, 0, stream>>>(h, batch, mw0, mb0, mw1, mb1, mw2, mb2, out);
}

// Round 13
// 555.040 us; speedup vs baseline: 1.1539x; 1.0072x over previous
//
#include <hip/hip_runtime.h>
#include <hip/hip_bf16.h>

#define N_NODES 50000
#define N_EDGES 800000
#define N_GRAPHS 128
#define HID 128
#define NK 3
#define NL 4
#define NC 10
#define BN_EPS 1e-5f
#define SCAN_G ((N_NODES + 255) / 256)
#define NSLICE 32

// degree histogram bucketing
#define BKT_SZ 8192
#define NBKT 7                    // ceil(50000/8192)
#define NCHK 64
#define CHK_E (N_EDGES / NCHK)    // 12500

typedef __attribute__((ext_vector_type(8))) _Float16 half8;
typedef __attribute__((ext_vector_type(4))) float floatx4;
typedef __attribute__((ext_vector_type(2))) float float2v;
typedef __attribute__((ext_vector_type(2))) _Float16 half2v;
typedef __attribute__((ext_vector_type(4))) _Float16 half4v;

__device__ __forceinline__ float tanh_fast(float x) {
    float ax = fabsf(x);
    float t = __expf(-2.0f * ax);
    float r = (1.0f - t) / (1.0f + t);
    return copysignf(r, x);
}

// ------- degree histogram: per-(bucket,chunk) partials, LDS atomics only
__global__ __launch_bounds__(256) void hist_part_kernel(const int* __restrict__ row,
                                                        const int* __restrict__ col,
                                                        int* __restrict__ pr,
                                                        int* __restrict__ pc) {
    __shared__ int hh[BKT_SZ];
    int b = blockIdx.x / NCHK, c = blockIdx.x % NCHK;
    const int* arr = blockIdx.y ? col : row;
    int* out = blockIdx.y ? pc : pr;
    int tid = threadIdx.x;
    for (int i = tid; i < BKT_SZ; i += 256) hh[i] = 0;
    __syncthreads();
    int base = b * BKT_SZ;
    int e0 = c * CHK_E, e1 = e0 + CHK_E;
    for (int e = e0 + tid; e < e1; e += 256) {
        int uv = arr[e] - base;
        if ((unsigned)uv < BKT_SZ) atomicAdd(&hh[uv], 1);
    }
    __syncthreads();
    size_t ob = ((size_t)b * NCHK + c) * BKT_SZ;
    for (int i = tid; i < BKT_SZ; i += 256) out[ob + i] = hh[i];
}

// reduce partials -> degr/degc
__global__ __launch_bounds__(256) void hist_reduce_kernel(const int* __restrict__ pr,
                                                          const int* __restrict__ pc,
                                                          int* __restrict__ degr,
                                                          int* __restrict__ degc) {
    int n = blockIdx.x * 256 + threadIdx.x;
    if (n >= N_NODES) return;
    int b = n / BKT_SZ, off = n - b * BKT_SZ;
    size_t base = (size_t)b * NCHK * BKT_SZ + off;
    int sr = 0, sc = 0;
    for (int c = 0; c < NCHK; ++c) {
        size_t idx = base + (size_t)c * BKT_SZ;
        sr += pr[idx];
        sc += pc[idx];
    }
    degr[n] = sr;
    degc[n] = sc;
}

// ------------------------------------------------ hierarchical scan (3 kernels)
__global__ __launch_bounds__(256) void scan1_kernel(const int* __restrict__ degc,
                                                    int* __restrict__ csr_off,
                                                    int* __restrict__ blocksum) {
    __shared__ int buf[256];
    int tid = threadIdx.x;
    int i = blockIdx.x * 256 + tid;
    int v = (i < N_NODES) ? degc[i] : 0;
    buf[tid] = v;
    __syncthreads();
    for (int d = 1; d < 256; d <<= 1) {
        int t = (tid >= d) ? buf[tid - d] : 0;
        __syncthreads();
        buf[tid] += t;
        __syncthreads();
    }
    if (i < N_NODES) csr_off[i] = buf[tid] - v;
    if (tid == 255) blocksum[blockIdx.x] = buf[255];
}

__global__ __launch_bounds__(256) void scan2_kernel(int* __restrict__ blocksum) {
    __shared__ int buf[256];
    int tid = threadIdx.x;
    int v = (tid < SCAN_G) ? blocksum[tid] : 0;
    buf[tid] = v;
    __syncthreads();
    for (int d = 1; d < 256; d <<= 1) {
        int t = (tid >= d) ? buf[tid - d] : 0;
        __syncthreads();
        buf[tid] += t;
        __syncthreads();
    }
    if (tid < SCAN_G) blocksum[tid] = buf[tid] - v;   // exclusive, in place
}

__global__ __launch_bounds__(256) void scan3_kernel(const int* __restrict__ blocksum,
                                                    int* __restrict__ csr_off,
                                                    int* __restrict__ cursor) {
    int i = blockIdx.x * 256 + threadIdx.x;
    if (i < N_NODES) {
        int v = csr_off[i] + blocksum[blockIdx.x];
        csr_off[i] = v;
        cursor[i] = v;
    }
    if (i == 0) csr_off[N_NODES] = N_EDGES;
}

// ---------- counting-sort: scatter only the permutation (4-B writes)
__global__ void fill_perm_kernel(const int* __restrict__ col,
                                 int* __restrict__ cursor, int* __restrict__ perm) {
    int e = blockIdx.x * blockDim.x + threadIdx.x;
    if (e >= N_EDGES) return;
    int pos = atomicAdd(&cursor[col[e]], 1);
    perm[pos] = e;
}

// ---- per-layer weight records, written COALESCED in CSR position order
// wrec[l][pos] = { row_byte_off, w0, w1, w2 }
__global__ void edge_w_rec_kernel(const int* __restrict__ perm,
                                  const int* __restrict__ row, const int* __restrict__ col,
                                  const int* __restrict__ degr, const int* __restrict__ degc,
                                  const float* __restrict__ pp_w, const float* __restrict__ pp_b,
                                  const float* __restrict__ mu, const float* __restrict__ isig,
                                  int4* __restrict__ wrec) {
    int pos = blockIdx.x * blockDim.x + threadIdx.x;
    if (pos >= N_EDGES) return;
    int e = perm[pos];
    int r = row[e], c = col[e];
    float px = rsqrtf((float)degr[r] + 1.0f);
    float py = rsqrtf((float)degc[c] + 1.0f);
    int roff = r << 8;   // byte offset into fp16 h row (256 B)
#pragma unroll
    for (int l = 0; l < NL; ++l) {
        float ps0 = tanh_fast(px * pp_w[l * 4 + 0] + py * pp_w[l * 4 + 1] + pp_b[l * 2 + 0]);
        float ps1 = tanh_fast(px * pp_w[l * 4 + 2] + py * pp_w[l * 4 + 3] + pp_b[l * 2 + 1]);
        float w[NK];
#pragma unroll
        for (int k = 0; k < NK; ++k) {
            float d0 = ps0 - mu[l * 6 + k * 2 + 0], d1 = ps1 - mu[l * 6 + k * 2 + 1];
            float s0 = isig[l * 6 + k * 2 + 0],     s1 = isig[l * 6 + k * 2 + 1];
            w[k] = __expf(-0.5f * (d0 * d0 * s0 * s0 + d1 * d1 * s1 * s1));
        }
        wrec[(size_t)l * N_EDGES + pos] =
            make_int4(roff, __float_as_int(w[0]), __float_as_int(w[1]), __float_as_int(w[2]));
    }
}

// --------------------- fp32 -> fp16 convert (two sources, one dispatch)
__global__ void cvt16_dual_kernel(const float4* __restrict__ a, int n4a,
                                  const float4* __restrict__ b, int n4b,
                                  half4v* __restrict__ da, half4v* __restrict__ db) {
    int i = blockIdx.x * blockDim.x + threadIdx.x;
    const float4* src; half4v* dst; int idx;
    if (i < n4a) { src = a; dst = da; idx = i; }
    else if (i < n4a + n4b) { src = b; dst = db; idx = i - n4a; }
    else return;
    float4 f = src[idx];
    half4v o;
    o.x = (_Float16)f.x; o.y = (_Float16)f.y; o.z = (_Float16)f.z; o.w = (_Float16)f.w;
    dst[idx] = o;
}

// ---------- fc_w transpose -> fp16: w2t[l][j][k*H+i] = fc_w[l][k*H+j][i]
__global__ void transpose_fc16_kernel(const float* __restrict__ fc_w,
                                      _Float16* __restrict__ w2t) {
    int idx = blockIdx.x * blockDim.x + threadIdx.x;
    if (idx >= NL * NK * HID * HID) return;
    int i = idx & (HID - 1);
    int j = (idx >> 7) & (HID - 1);
    int kl = idx >> 14;          // l*3 + k
    int k = kl % 3;
    int l = kl / 3;
    w2t[((size_t)(l * HID + j)) * (NK * HID) + k * HID + i] = (_Float16)fc_w[idx];
}

// -------------------------------------------------- fp16 MFMA GEMM
// C16[M x 128] = A[M x Kd] @ W[128 x Kd]^T (+bias). 128x128 block tile.
// Optional BN stats into slice blockIdx.x&31.
__global__ __launch_bounds__(256) void gemm_f16_kernel(
        const _Float16* __restrict__ A, const _Float16* __restrict__ W,
        const float* __restrict__ bias, _Float16* __restrict__ C16,
        float* __restrict__ bnsum, int M, int Kd) {
    __shared__ _Float16 sA[128 * 40], sB[128 * 40];   // stride 40 halfs
    __shared__ float bsum[HID], bsq[HID];
    int tid = threadIdx.x;
    if (bnsum && tid < HID) { bsum[tid] = 0.f; bsq[tid] = 0.f; }
    int bm = blockIdx.x * 128;
    int wave = tid >> 6, lane = tid & 63;
    int ln = lane & 15, quad = lane >> 4;
    int wy = wave >> 1, wx = wave & 1;
    int srow = tid >> 2, scol = (tid & 3) << 3;
    floatx4 acc[4][4] = {};
    const half8 zv = {0, 0, 0, 0, 0, 0, 0, 0};

    half8 pA[2], pB[2];
    bool av0 = (bm + srow) < M, av1 = (bm + srow + 64) < M;
    const size_t aoff0 = (size_t)(bm + srow) * Kd + scol;
    const size_t aoff1 = (size_t)(bm + srow + 64) * Kd + scol;
    const size_t woff0 = (size_t)srow * Kd + scol;
    const size_t woff1 = (size_t)(srow + 64) * Kd + scol;

#define LOAD_TILE(K0)                                                          \
    do {                                                                       \
        pB[0] = *(const half8*)(W + woff0 + (K0));                             \
        pB[1] = *(const half8*)(W + woff1 + (K0));                             \
        pA[0] = av0 ? *(const half8*)(A + aoff0 + (K0)) : zv;                  \
        pA[1] = av1 ? *(const half8*)(A + aoff1 + (K0)) : zv;                  \
    } while (0)

    LOAD_TILE(0);
    for (int k0 = 0; k0 < Kd; k0 += 32) {
        __syncthreads();
#pragma unroll
        for (int rep = 0; rep < 2; ++rep) {
            int r = srow + rep * 64;
            *(half8*)&sA[r * 40 + scol] = pA[rep];
            *(half8*)&sB[r * 40 + scol] = pB[rep];
        }
        __syncthreads();
        if (k0 + 32 < Kd) LOAD_TILE(k0 + 32);   // overlaps with MFMA below
        half8 a[4], b[4];
        int kq = quad * 8;
#pragma unroll
        for (int i = 0; i < 4; ++i) {
            a[i] = *(const half8*)&sA[(wy * 64 + i * 16 + ln) * 40 + kq];
            b[i] = *(const half8*)&sB[(wx * 64 + i * 16 + ln) * 40 + kq];
        }
#pragma unroll
        for (int i = 0; i < 4; ++i)
#pragma unroll
            for (int j = 0; j < 4; ++j)
                acc[i][j] = __builtin_amdgcn_mfma_f32_16x16x32_f16(a[i], b[j], acc[i][j], 0, 0, 0);
    }
#undef LOAD_TILE

    // epilogue: C/D layout col = lane&15, row = quad*4 + reg
#pragma unroll
    for (int j = 0; j < 4; ++j) {
        int gc = wx * 64 + j * 16 + ln;
        float bv = bias ? bias[gc] : 0.f;
#pragma unroll
        for (int i = 0; i < 4; ++i) {
#pragma unroll
            for (int r = 0; r < 4; ++r) {
                int gr = bm + wy * 64 + i * 16 + quad * 4 + r;
                if (gr < M) C16[(size_t)gr * HID + gc] = (_Float16)(acc[i][j][r] + bv);
            }
        }
    }
    if (bnsum) {
        // rows beyond M accumulated zeros (A loaded as 0, no bias) -> safe
#pragma unroll
        for (int j = 0; j < 4; ++j) {
            float s = 0.f, q = 0.f;
#pragma unroll
            for (int i = 0; i < 4; ++i)
#pragma unroll
                for (int r = 0; r < 4; ++r) { float v = acc[i][j][r]; s += v; q += v * v; }
            s += __shfl_xor(s, 16); s += __shfl_xor(s, 32);
            q += __shfl_xor(q, 16); q += __shfl_xor(q, 32);
            if (quad == 0) {
                atomicAdd(&bsum[wx * 64 + j * 16 + ln], s);
                atomicAdd(&bsq[wx * 64 + j * 16 + ln], q);
            }
        }
        __syncthreads();
        float* slice = bnsum + (blockIdx.x & (NSLICE - 1)) * (2 * HID);
        if (tid < HID) {
            atomicAdd(&slice[tid],       bsum[tid]);
            atomicAdd(&slice[HID + tid], bsq[tid]);
        }
    }
}

// ---- reduce BN slices -> fused scale/shift (one tiny block per layer)
__global__ __launch_bounds__(128) void bn_finalize_kernel(const float* __restrict__ slices,
                                                          const float* __restrict__ gamma,
                                                          const float* __restrict__ beta,
                                                          float* __restrict__ sc_sh) {
    int t = threadIdx.x;   // channel
    float s = 0.f, q = 0.f;
    for (int sl = 0; sl < NSLICE; ++sl) {
        s += slices[sl * (2 * HID) + t];
        q += slices[sl * (2 * HID) + HID + t];
    }
    const float invN = 1.0f / (float)N_NODES;
    float mean = s * invN;
    float var = q * invN - mean * mean;
    float scale = gamma[t] * rsqrtf(var + BN_EPS);
    sc_sh[t] = scale;
    sc_sh[HID + t] = beta[t] - mean * scale;
}

// ----------- CSR aggregation: fp16 h gather, precomputed weight records.
__global__ __launch_bounds__(256) void aggregate_kernel(const int* __restrict__ csr_off,
                                                        const int4* __restrict__ wrec,
                                                        const char* __restrict__ h16,
                                                        _Float16* __restrict__ u) {
    int wave = threadIdx.x >> 6;
    int lane = threadIdx.x & 63;
    int n = blockIdx.x * 4 + wave;
    if (n >= N_NODES) return;
    int beg = csr_off[n], end = csr_off[n + 1];
    const char* hb = h16 + lane * 4;
    float2v a0 = {0.f, 0.f}, a1 = {0.f, 0.f}, a2 = {0.f, 0.f};
    for (int chunk = beg; chunk < end; chunk += 64) {
        int ce = chunk + lane;
        int roff = 0;
        float w0 = 0.f, w1 = 0.f, w2 = 0.f;
        if (ce < end) {
            int4 md = wrec[ce];
            roff = md.x;
            w0 = __int_as_float(md.y);
            w1 = __int_as_float(md.z);
            w2 = __int_as_float(md.w);
        }
        int m = end - chunk; if (m > 64) m = 64;
        int t = 0;
        for (; t + 16 <= m; t += 16) {
            int ro[16];
#pragma unroll
            for (int s = 0; s < 16; ++s) ro[s] = __shfl(roff, t + s);
            half2v hv[16];
#pragma unroll
            for (int s = 0; s < 16; ++s) hv[s] = *(const half2v*)(hb + (unsigned)ro[s]);
#pragma unroll
            for (int g = 0; g < 4; ++g) {
                float wx[4], wy[4], wz[4];
#pragma unroll
                for (int s = 0; s < 4; ++s) {
                    wx[s] = __shfl(w0, t + g * 4 + s);
                    wy[s] = __shfl(w1, t + g * 4 + s);
                    wz[s] = __shfl(w2, t + g * 4 + s);
                }
#pragma unroll
                for (int s = 0; s < 4; ++s) {
                    half2v hh = hv[g * 4 + s];
                    float2v hf = {(float)hh.x, (float)hh.y};
                    a0 += wx[s] * hf;
                    a1 += wy[s] * hf;
                    a2 += wz[s] * hf;
                }
            }
        }
        for (; t + 8 <= m; t += 8) {
            int ro[8];
#pragma unroll
            for (int s = 0; s < 8; ++s) ro[s] = __shfl(roff, t + s);
            half2v hv[8];
#pragma unroll
            for (int s = 0; s < 8; ++s) hv[s] = *(const half2v*)(hb + (unsigned)ro[s]);
            float wx[8], wy[8], wz[8];
#pragma unroll
            for (int s = 0; s < 8; ++s) {
                wx[s] = __shfl(w0, t + s);
                wy[s] = __shfl(w1, t + s);
                wz[s] = __shfl(w2, t + s);
            }
#pragma unroll
            for (int s = 0; s < 8; ++s) {
                float2v hf = {(float)hv[s].x, (float)hv[s].y};
                a0 += wx[s] * hf;
                a1 += wy[s] * hf;
                a2 += wz[s] * hf;
            }
        }
        for (; t < m; ++t) {
            int ro = __shfl(roff, t);
            float wx = __shfl(w0, t), wy = __shfl(w1, t), wz = __shfl(w2, t);
            half2v hv = *(const half2v*)(hb + (unsigned)ro);
            float2v hf = {(float)hv.x, (float)hv.y};
            a0 += wx * hf;
            a1 += wy * hf;
            a2 += wz * hf;
        }
    }
    size_t base = (size_t)n * 384 + lane * 2;
    half2v o0, o1, o2;
    o0.x = (_Float16)a0.x; o0.y = (_Float16)a0.y;
    o1.x = (_Float16)a1.x; o1.y = (_Float16)a1.y;
    o2.x = (_Float16)a2.x; o2.y = (_Float16)a2.y;
    *(half2v*)(u + base)       = o0;
    *(half2v*)(u + base + 128) = o1;
    *(half2v*)(u + base + 256) = o2;
}

// ------- BN apply (fused scale/shift) + ReLU + residual, all-fp16 h
__global__ void bn_apply_kernel(half4v* __restrict__ h16,
                                const half4v* __restrict__ agg16,
                                const float* __restrict__ sc_sh) {
    int idx = blockIdx.x * blockDim.x + threadIdx.x;
    if (idx >= N_NODES * HID / 4) return;
    int c = (idx & 31) * 4;
    half4v a = agg16[idx];
    half4v hv = h16[idx];
    half4v o16;
#pragma unroll
    for (int j = 0; j < 4; ++j) {
        float hn = (float)a[j] * sc_sh[c + j] + sc_sh[HID + c + j];
        o16[j] = (_Float16)((float)hv[j] + fmaxf(hn, 0.f));
    }
    h16[idx] = o16;
}

// -------------------------------------------- fused readout + 3-layer MLP
__global__ __launch_bounds__(128) void readout_mlp_kernel(const _Float16* __restrict__ h16,
                                                          const int* __restrict__ batch,
                                                          const float* __restrict__ w0, const float* __restrict__ b0,
                                                          const float* __restrict__ w1, const float* __restrict__ b1,
                                                          const float* __restrict__ w2, const float* __restrict__ b2,
                                                          float* __restrict__ out) {
    __shared__ float hg[128];
    __shared__ float z0[64];
    __shared__ float z1[32];
    __shared__ int range[2];
    int g = blockIdx.x;
    int tid = threadIdx.x;
    if (tid == 0) {
        int lo = 0, hi = N_NODES;
        while (lo < hi) { int mid = (lo + hi) >> 1; if (batch[mid] < g) lo = mid + 1; else hi = mid; }
        range[0] = lo;
        hi = N_NODES;
        while (lo < hi) { int mid = (lo + hi) >> 1; if (batch[mid] < g + 1) lo = mid + 1; else hi = mid; }
        range[1] = lo;
    }
    __syncthreads();
    int lo = range[0], hi = range[1];
    float s0 = 0.f, s1 = 0.f, s2 = 0.f, s3 = 0.f;
    int n = lo;
    for (; n + 4 <= hi; n += 4) {
        s0 += (float)h16[(size_t)n * HID + tid];
        s1 += (float)h16[(size_t)(n + 1) * HID + tid];
        s2 += (float)h16[(size_t)(n + 2) * HID + tid];
        s3 += (float)h16[(size_t)(n + 3) * HID + tid];
    }
    for (; n < hi; ++n) s0 += (float)h16[(size_t)n * HID + tid];
    float s = (s0 + s1) + (s2 + s3);
    int cnt = hi - lo; if (cnt < 1) cnt = 1;
    hg[tid] = s / (float)cnt;
    __syncthreads();
    if (tid < 64) {
        float a = b0[tid];
        for (int i = 0; i < 128; ++i) a += hg[i] * w0[tid * 128 + i];
        z0[tid] = fmaxf(a, 0.f);
    }
    __syncthreads();
    if (tid < 32) {
        float a = b1[tid];
        for (int i = 0; i < 64; ++i) a += z0[i] * w1[tid * 64 + i];
        z1[tid] = fmaxf(a, 0.f);
    }
    __syncthreads();
    if (tid < 10) {
        float a = b2[tid];
        for (int i = 0; i < 32; ++i) a += z1[i] * w2[tid * 32 + i];
        out[g * NC + tid] = a;
    }
}

// ----------------------------------------------------------------- launch
extern "C" void kernel_launch(void* const* d_in, const int* in_sizes, int n_in,
                              void* d_out, int out_size, void* d_ws, size_t ws_size,
                              hipStream_t stream) {
    const float* feature = (const float*)d_in[0];
    const int*   edge    = (const int*)d_in[1];
    const int*   row     = edge;
    const int*   col     = edge + N_EDGES;
    const int*   batch   = (const int*)d_in[2];
    const float* emb_w   = (const float*)d_in[3];
    const float* emb_b   = (const float*)d_in[4];
    const float* fc_w    = (const float*)d_in[5];
    const float* mu      = (const float*)d_in[6];
    const float* isig    = (const float*)d_in[7];
    const float* gamma   = (const float*)d_in[8];
    const float* beta    = (const float*)d_in[9];
    const float* pp_w    = (const float*)d_in[10];
    const float* pp_b    = (const float*)d_in[11];
    const float* mw0     = (const float*)d_in[12];
    const float* mb0     = (const float*)d_in[13];
    const float* mw1     = (const float*)d_in[14];
    const float* mb1     = (const float*)d_in[15];
    const float* mw2     = (const float*)d_in[16];
    const float* mb2     = (const float*)d_in[17];
    float* out = (float*)d_out;

    // workspace carve-up (256B aligned)
    char* ws = (char*)d_ws;
    size_t off = 0;
    auto carve = [&](size_t bytes) { size_t o = off; off = (off + bytes + 255) & ~(size_t)255; return o; };
    _Float16* h16   = (_Float16*)(ws + carve((size_t)N_NODES * HID * 2));
    _Float16* u     = (_Float16*)(ws + carve((size_t)N_NODES * NK * HID * 2));
    _Float16* agg16 = (_Float16*)(ws + carve((size_t)N_NODES * HID * 2));
    int* perm       = (int*)(ws + carve((size_t)N_EDGES * 4));
    int4* wrec      = (int4*)(ws + carve((size_t)NL * N_EDGES * 16));
    _Float16* w2t   = (_Float16*)(ws + carve((size_t)NL * HID * NK * HID * 2));
    _Float16* f16   = (_Float16*)(ws + carve((size_t)N_NODES * HID * 2));
    _Float16* e16   = (_Float16*)(ws + carve((size_t)HID * HID * 2));
    int* degr       = (int*)(ws + carve((size_t)N_NODES * 4));
    int* degc       = (int*)(ws + carve((size_t)N_NODES * 4));
    int* csr_off    = (int*)(ws + carve((size_t)(N_NODES + 1) * 4));
    int* cursor     = (int*)(ws + carve((size_t)N_NODES * 4));
    int* blocksum   = (int*)(ws + carve((size_t)SCAN_G * 4));
    int* pr         = (int*)(ws + carve((size_t)NBKT * NCHK * BKT_SZ * 4));
    int* pc         = (int*)(ws + carve((size_t)NBKT * NCHK * BKT_SZ * 4));
    float* bnsum    = (float*)(ws + carve((size_t)NL * NSLICE * 2 * HID * 4));
    float* bnfin    = (float*)(ws + carve((size_t)NL * 2 * HID * 4));
    (void)ws_size; (void)in_sizes; (void)n_in; (void)out_size;

    hipMemsetAsync(bnsum, 0, (size_t)NL * NSLICE * 2 * HID * 4, stream);

    hist_part_kernel<<<dim3(NBKT * NCHK, 2), 256, 0, stream>>>(row, col, pr, pc);
    hist_reduce_kernel<<<(N_NODES + 255) / 256, 256, 0, stream>>>(pr, pc, degr, degc);
    scan1_kernel<<<SCAN_G, 256, 0, stream>>>(degc, csr_off, blocksum);
    scan2_kernel<<<1, 256, 0, stream>>>(blocksum);
    scan3_kernel<<<SCAN_G, 256, 0, stream>>>(blocksum, csr_off, cursor);
    fill_perm_kernel<<<(N_EDGES + 255) / 256, 256, 0, stream>>>(col, cursor, perm);
    edge_w_rec_kernel<<<(N_EDGES + 255) / 256, 256, 0, stream>>>(
        perm, row, col, degr, degc, pp_w, pp_b, mu, isig, wrec);

    cvt16_dual_kernel<<<((N_NODES * HID + HID * HID) / 4 + 255) / 256, 256, 0, stream>>>(
        (const float4*)feature, N_NODES * HID / 4, (const float4*)emb_w, HID * HID / 4,
        (half4v*)f16, (half4v*)e16);
    transpose_fc16_kernel<<<(NL * NK * HID * HID + 255) / 256, 256, 0, stream>>>(fc_w, w2t);

    // h16 = feature @ emb_w^T + emb_b
    gemm_f16_kernel<<<(N_NODES + 127) / 128, 256, 0, stream>>>(
        f16, e16, emb_b, h16, nullptr, N_NODES, HID);

    for (int l = 0; l < NL; ++l) {
        aggregate_kernel<<<(N_NODES + 3) / 4, 256, 0, stream>>>(
            csr_off, wrec + (size_t)l * N_EDGES, (const char*)h16, u);
        gemm_f16_kernel<<<(N_NODES + 127) / 128, 256, 0, stream>>>(
            u, w2t + (size_t)l * HID * NK * HID, nullptr, agg16,
            bnsum + (size_t)l * NSLICE * 2 * HID, N_NODES, NK * HID);
        bn_finalize_kernel<<<1, 128, 0, stream>>>(
            bnsum + (size_t)l * NSLICE * 2 * HID, gamma + l * HID, beta + l * HID,
            bnfin + l * 2 * HID);
        bn_apply_kernel<<<(N_NODES * HID / 4 + 255) / 256, 256, 0, stream>>>(
            (half4v*)h16, (const half4v*)agg16, bnfin + l * 2 * HID);
    }

    readout_mlp_kernel<<<N_GRAPHS, 128, 0, stream>>>(h16, batch, mw0, mb0, mw1, mb1, mw2, mb2, out);
}